// Round 3
// baseline (323.727 us; speedup 1.0000x reference)
//
#include <hip/hip_runtime.h>
#include <stdint.h>

#define N_NODES 100000
#define N_EDGES 3200000
#define F_IN 256
#define HID 16
#define NCLS 7

#define NBUCK 196        // ceil(100000 / 512) buckets of 512 nodes (dst >> 9)
#define BCAP 20480       // capacity per bucket (avg 16384 -> 32 sigma headroom)
#define EPB 4096         // edges per block in bucket_kernel (16 per thread)

using frag8 = __attribute__((ext_vector_type(8))) short;
using f32x4 = __attribute__((ext_vector_type(4))) float;

__device__ inline short f32_to_bf16_rn(float f) {
    uint32_t u = __float_as_uint(f);
    uint32_t r = (u + 0x7FFF + ((u >> 16) & 1)) >> 16;
    return (short)r;
}
__device__ inline float bf16_to_f32(short s) {
    return __uint_as_float(((uint32_t)(uint16_t)s) << 16);
}

// ---------------- edge dtype detection (int64 vs int32) -------------------
__global__ void detect_kernel(const uint32_t* edge_raw, int* flag) {
    __shared__ int s_any;
    if (threadIdx.x == 0) s_any = 0;
    __syncthreads();
    uint32_t v = 0;
    for (int i = 0; i < 16; ++i) {
        int idx = threadIdx.x * 16 + i;
        v |= edge_raw[2 * idx + 1];
    }
    if (v) atomicOr(&s_any, 1);
    __syncthreads();
    if (threadIdx.x == 0) *flag = (s_any == 0) ? 1 : 0;  // 1 => int64 layout
}

// ---------------- pass 1: bin edges into 196 dst-buckets -------------------
__global__ __launch_bounds__(256) void bucket_kernel(const void* edge_raw, const int* flag,
                                                     int* gcount, uint32_t* temp) {
    __shared__ int cnt[NBUCK];
    __shared__ int base[NBUCK];
    int t = threadIdx.x;
    if (t < NBUCK) cnt[t] = 0;
    __syncthreads();
    int is64 = *flag;
    int e0 = blockIdx.x * EPB;
    uint32_t val[16];
    int rb[16];
#pragma unroll
    for (int k = 0; k < 16; ++k) {
        int e = e0 + k * 256 + t;
        if (e < N_EDGES) {
            int s, d;
            if (is64) {
                const long long* p = (const long long*)edge_raw;
                s = (int)p[e]; d = (int)p[N_EDGES + e];
            } else {
                const int* p = (const int*)edge_raw;
                s = p[e]; d = p[N_EDGES + e];
            }
            int b = d >> 9;
            val[k] = ((uint32_t)s << 9) | (uint32_t)(d & 511);
            int r = atomicAdd(&cnt[b], 1);
            rb[k] = (b << 16) | r;
        } else {
            rb[k] = -1;
        }
    }
    __syncthreads();
    if (t < NBUCK) base[t] = atomicAdd(&gcount[t], cnt[t]);
    __syncthreads();
#pragma unroll
    for (int k = 0; k < 16; ++k) {
        if (rb[k] >= 0) {
            int b = rb[k] >> 16;
            int pos = base[b] + (rb[k] & 0xFFFF);
            if (pos < BCAP) temp[(size_t)b * BCAP + pos] = val[k];
        }
    }
}

// ---------------- scan of bucket counts ------------------------------------
__global__ void bscan_kernel(const int* gcount, int* bstart) {
    __shared__ int sh[256];
    int t = threadIdx.x;
    int v = (t < NBUCK) ? gcount[t] : 0;
    sh[t] = v;
    __syncthreads();
    for (int off = 1; off < 256; off <<= 1) {
        int a = (t >= off) ? sh[t - off] : 0;
        __syncthreads();
        sh[t] += a;
        __syncthreads();
    }
    if (t < NBUCK) bstart[t] = sh[t] - v;
    if (t == 0) bstart[NBUCK] = N_EDGES;
}

// ---------------- pass 2: per-bucket CSR build (no global atomics) ---------
__global__ __launch_bounds__(256) void build_kernel(const uint32_t* temp, const int* gcount,
                                                    const int* bstart, int* row_start,
                                                    float* dinv, int* ssort) {
    __shared__ int hist[512];
    __shared__ int sh[256];
    __shared__ int cur[512];
    int b = blockIdx.x;
    int t = threadIdx.x;
    int cnt = min(gcount[b], BCAP);
    int bs = bstart[b];
    const uint32_t* tp = temp + (size_t)b * BCAP;
    hist[t] = 0; hist[t + 256] = 0;
    __syncthreads();
    for (int i = t; i < cnt; i += 256) atomicAdd(&hist[tp[i] & 511], 1);
    __syncthreads();
    int d0 = hist[2 * t], d1 = hist[2 * t + 1];
    int ts = d0 + d1;
    sh[t] = ts;
    __syncthreads();
    for (int off = 1; off < 256; off <<= 1) {
        int a = (t >= off) ? sh[t - off] : 0;
        __syncthreads();
        sh[t] += a;
        __syncthreads();
    }
    int ex = sh[t] - ts;
    int node0 = b * 512 + 2 * t;
    cur[2 * t] = ex;
    cur[2 * t + 1] = ex + d0;
    if (node0 < N_NODES)     { row_start[node0]     = bs + ex;      dinv[node0]     = rsqrtf((float)(d0 + 1)); }
    if (node0 + 1 < N_NODES) { row_start[node0 + 1] = bs + ex + d0; dinv[node0 + 1] = rsqrtf((float)(d1 + 1)); }
    __syncthreads();
    for (int i = t; i < cnt; i += 256) {
        uint32_t v = tp[i];
        int pos = atomicAdd(&cur[v & 511], 1);
        ssort[bs + pos] = (int)(v >> 9);
    }
    if (b == 0 && t == 0) row_start[N_NODES] = N_EDGES;
}

// ---------------- GEMM1 (MFMA bf16 split-precision): y = dinv*(x@W1) -------
#define XST 260   // 256 + 4 floats pad; 1040 B row stride, 16B aligned
__global__ __launch_bounds__(128) void gemm1_kernel(const float* __restrict__ x,
                                                    const float* __restrict__ W1,
                                                    const float* __restrict__ dinv,
                                                    float* __restrict__ y) {
    __shared__ float xs[32 * XST];
    int t = threadIdx.x;
    int lane = t & 63;
    int wid = t >> 6;      // wave 0/1: rows 0-15 / 16-31
    int col = lane & 15;   // N index (and M row index for A-frag)
    int kg = lane >> 4;    // k-group 0..3
    // --- W1 fragments (hi/lo bf16) in registers: same for all blocks -------
    frag8 whi[8], wlo[8];
#pragma unroll
    for (int s = 0; s < 8; ++s) {
#pragma unroll
        for (int j = 0; j < 8; ++j) {
            int k = s * 32 + kg * 8 + j;
            float wv = W1[k * HID + col];
            short h = f32_to_bf16_rn(wv);
            short l = f32_to_bf16_rn(wv - bf16_to_f32(h));
            whi[s][j] = h;
            wlo[s][j] = l;
        }
    }
    // --- stage 32 rows of x (f32) ------------------------------------------
    int v0 = blockIdx.x * 32;
    for (int i = t; i < 32 * 64; i += 128) {
        int r = i >> 6, c4 = i & 63;
        float4 val = ((const float4*)(x + (size_t)(v0 + r) * F_IN))[c4];
        *((float4*)(xs + r * XST + c4 * 4)) = val;
    }
    __syncthreads();
    const float* xrow = xs + (wid * 16 + col) * XST + kg * 8;
    f32x4 acc = {0.f, 0.f, 0.f, 0.f};
#pragma unroll
    for (int s = 0; s < 8; ++s) {
        float4 a = *((const float4*)(xrow + s * 32));
        float4 b = *((const float4*)(xrow + s * 32 + 4));
        float xv[8] = {a.x, a.y, a.z, a.w, b.x, b.y, b.z, b.w};
        frag8 ahi, alo;
#pragma unroll
        for (int j = 0; j < 8; ++j) {
            short h = f32_to_bf16_rn(xv[j]);
            short l = f32_to_bf16_rn(xv[j] - bf16_to_f32(h));
            ahi[j] = h; alo[j] = l;
        }
        acc = __builtin_amdgcn_mfma_f32_16x16x32_bf16(alo, whi[s], acc, 0, 0, 0);
        acc = __builtin_amdgcn_mfma_f32_16x16x32_bf16(ahi, wlo[s], acc, 0, 0, 0);
        acc = __builtin_amdgcn_mfma_f32_16x16x32_bf16(ahi, whi[s], acc, 0, 0, 0);
    }
    // C layout: col = lane&15, tile row = kg*4 + reg (m89-verified)
#pragma unroll
    for (int r = 0; r < 4; ++r) {
        int gr = v0 + wid * 16 + kg * 4 + r;
        y[(size_t)gr * HID + col] = acc[r] * dinv[gr];
    }
}

// ---------------- shared gather+reduce for aggregation ---------------------
__device__ inline float4 shfl_xor4(float4 a, int m) {
    float4 r;
    r.x = __shfl_xor(a.x, m); r.y = __shfl_xor(a.y, m);
    r.z = __shfl_xor(a.z, m); r.w = __shfl_xor(a.w, m);
    return r;
}

// returns this lane's quad (q = lane&3) of h = relu(dinv*(sum_in y + y_self)+b)
__device__ inline float4 gather_reduce(const float* __restrict__ y,
                                       const float* __restrict__ dinvp,
                                       const float* __restrict__ bias,
                                       const int* __restrict__ row_start,
                                       const int* __restrict__ ssort,
                                       int v, int lane, float& dv_out) {
    int start = row_start[v];
    int end = row_start[v + 1];
    int q = lane & 3;
    int eg = lane >> 2;
    float4 acc = make_float4(0.f, 0.f, 0.f, 0.f);
    for (int base = start; base < end; base += 16) {
        int e = base + eg;
        if (e < end) {
            int s = ssort[e];
            float4 yv = *((const float4*)(y + (size_t)s * HID + q * 4));
            acc.x += yv.x; acc.y += yv.y; acc.z += yv.z; acc.w += yv.w;
        }
    }
#pragma unroll
    for (int m = 4; m < 64; m <<= 1) {
        acc.x += __shfl_xor(acc.x, m);
        acc.y += __shfl_xor(acc.y, m);
        acc.z += __shfl_xor(acc.z, m);
        acc.w += __shfl_xor(acc.w, m);
    }
    float4 self = *((const float4*)(y + (size_t)v * HID + q * 4));
    float dv = dinvp[v];
    float4 bv = *((const float4*)(bias + q * 4));
    float4 r;
    r.x = fmaxf(dv * (acc.x + self.x) + bv.x, 0.f);
    r.y = fmaxf(dv * (acc.y + self.y) + bv.y, 0.f);
    r.z = fmaxf(dv * (acc.z + self.z) + bv.z, 0.f);
    r.w = fmaxf(dv * (acc.w + self.w) + bv.w, 0.f);
    dv_out = dv;
    return r;
}

__device__ inline void broadcast_h(float4 r, int lane, float* hr) {
    int q = lane & 3;
    float4 a1 = shfl_xor4(r, 1);
    float4 a2 = shfl_xor4(r, 2);
    float4 a3 = shfl_xor4(r, 3);
    hr[q * 4 + 0] = r.x;  hr[q * 4 + 1] = r.y;  hr[q * 4 + 2] = r.z;  hr[q * 4 + 3] = r.w;
    int q1 = q ^ 1; hr[q1 * 4 + 0] = a1.x; hr[q1 * 4 + 1] = a1.y; hr[q1 * 4 + 2] = a1.z; hr[q1 * 4 + 3] = a1.w;
    int q2 = q ^ 2; hr[q2 * 4 + 0] = a2.x; hr[q2 * 4 + 1] = a2.y; hr[q2 * 4 + 2] = a2.z; hr[q2 * 4 + 3] = a2.w;
    int q3 = q ^ 3; hr[q3 * 4 + 0] = a3.x; hr[q3 * 4 + 1] = a3.y; hr[q3 * 4 + 2] = a3.z; hr[q3 * 4 + 3] = a3.w;
}

// ---------------- agg layer 1 fused with gemm2: y2 = dinv*(h1@W2) ----------
__global__ __launch_bounds__(256) void aggA_kernel(const float* __restrict__ y,
                                                   const float* __restrict__ dinvp,
                                                   const float* __restrict__ b1,
                                                   const float* __restrict__ W2,
                                                   const int* __restrict__ row_start,
                                                   const int* __restrict__ ssort,
                                                   float* __restrict__ y2) {
    int wid = (blockIdx.x * blockDim.x + threadIdx.x) >> 6;
    int lane = threadIdx.x & 63;
    int v = wid;
    if (v >= N_NODES) return;
    float dv;
    float4 r = gather_reduce(y, dinvp, b1, row_start, ssort, v, lane, dv);
    float hr[16];
    broadcast_h(r, lane, hr);
    if (lane < 16) {
        float a = 0.f;
#pragma unroll
        for (int j = 0; j < 16; ++j) a += hr[j] * W2[j * 16 + lane];
        y2[(size_t)v * HID + lane] = dv * a;
    }
}

// ---------------- agg layer 2 fused with output + log_softmax --------------
__global__ __launch_bounds__(256) void aggB_kernel(const float* __restrict__ y,
                                                   const float* __restrict__ dinvp,
                                                   const float* __restrict__ b2,
                                                   const float* __restrict__ Wout,
                                                   const float* __restrict__ bout,
                                                   const int* __restrict__ row_start,
                                                   const int* __restrict__ ssort,
                                                   float* __restrict__ out) {
    int wid = (blockIdx.x * blockDim.x + threadIdx.x) >> 6;
    int lane = threadIdx.x & 63;
    int v = wid;
    if (v >= N_NODES) return;
    float dv;
    float4 r = gather_reduce(y, dinvp, b2, row_start, ssort, v, lane, dv);
    float hr[16];
    broadcast_h(r, lane, hr);
    float lg = -1e30f;
    if (lane < NCLS) {
        float a = bout[lane];
#pragma unroll
        for (int j = 0; j < 16; ++j) a += hr[j] * Wout[j * NCLS + lane];
        lg = a;
    }
    float mx = lg;
#pragma unroll
    for (int m = 1; m < 8; m <<= 1) mx = fmaxf(mx, __shfl_xor(mx, m));
    float e = (lane < NCLS) ? expf(lg - mx) : 0.f;
    float ssum = e;
#pragma unroll
    for (int m = 1; m < 8; m <<= 1) ssum += __shfl_xor(ssum, m);
    if (lane < NCLS) {
        float lse = mx + logf(ssum);
        out[(size_t)v * NCLS + lane] = lg - lse;
    }
}

extern "C" void kernel_launch(void* const* d_in, const int* in_sizes, int n_in,
                              void* d_out, int out_size, void* d_ws, size_t ws_size,
                              hipStream_t stream) {
    const float* x    = (const float*)d_in[0];
    const void*  edge = d_in[1];
    const float* W1   = (const float*)d_in[2];
    const float* b1   = (const float*)d_in[3];
    const float* W2   = (const float*)d_in[4];
    const float* b2   = (const float*)d_in[5];
    const float* Wout = (const float*)d_in[6];
    const float* bout = (const float*)d_in[7];
    float* out = (float*)d_out;
    char* ws = (char*)d_ws;

    auto al = [](size_t v) { return (v + 255) & ~(size_t)255; };
    size_t o = 0;
    int*      flag      = (int*)(ws + o);      o = al(o + 4);
    int*      gcount    = (int*)(ws + o);      o = al(o + (size_t)NBUCK * 4);
    int*      bstart    = (int*)(ws + o);      o = al(o + (size_t)(NBUCK + 1) * 4);
    int*      row_start = (int*)(ws + o);      o = al(o + (size_t)(N_NODES + 1) * 4);
    float*    dinv      = (float*)(ws + o);    o = al(o + (size_t)N_NODES * 4);
    uint32_t* temp      = (uint32_t*)(ws + o); o = al(o + (size_t)NBUCK * BCAP * 4);
    int*      ssort     = (int*)(ws + o);      o = al(o + (size_t)N_EDGES * 4);
    float*    y1buf     = (float*)(ws + o);    o = al(o + (size_t)N_NODES * HID * 4);
    float*    y2buf     = (float*)(ws + o);    o = al(o + (size_t)N_NODES * HID * 4);

    hipMemsetAsync(gcount, 0, (size_t)NBUCK * 4, stream);
    detect_kernel<<<1, 256, 0, stream>>>((const uint32_t*)edge, flag);
    bucket_kernel<<<(N_EDGES + EPB - 1) / EPB, 256, 0, stream>>>(edge, flag, gcount, temp);
    bscan_kernel<<<1, 256, 0, stream>>>(gcount, bstart);
    build_kernel<<<NBUCK, 256, 0, stream>>>(temp, gcount, bstart, row_start, dinv, ssort);
    gemm1_kernel<<<N_NODES / 32, 128, 0, stream>>>(x, W1, dinv, y1buf);
    aggA_kernel<<<(N_NODES * 64) / 256, 256, 0, stream>>>(y1buf, dinv, b1, W2, row_start, ssort, y2buf);
    aggB_kernel<<<(N_NODES * 64) / 256, 256, 0, stream>>>(y2buf, dinv, b2, Wout, bout, row_start, ssort, out);
}

// Round 4
// 230.755 us; speedup vs baseline: 1.4029x; 1.4029x over previous
//
#include <hip/hip_runtime.h>
#include <stdint.h>

#define N_NODES 100000
#define N_EDGES 3200000
#define F_IN 256
#define HID 16
#define NCLS 7

#define NBUCK 196        // ceil(100000 / 512) buckets of 512 nodes (dst >> 9)
#define BCAP 20480       // capacity per bucket (avg 16384 -> 32 sigma headroom)
#define EPB 4096         // edges per block in bucket_kernel (16 per thread)

using frag8 = __attribute__((ext_vector_type(8))) short;
using f32x4 = __attribute__((ext_vector_type(4))) float;

__device__ inline short f32_to_bf16_rn(float f) {
    uint32_t u = __float_as_uint(f);
    uint32_t r = (u + 0x7FFF + ((u >> 16) & 1)) >> 16;
    return (short)r;
}
__device__ inline float bf16_to_f32(short s) {
    return __uint_as_float(((uint32_t)(uint16_t)s) << 16);
}

// ---------------- edge dtype detection (int64 vs int32) -------------------
__global__ void detect_kernel(const uint32_t* edge_raw, int* flag) {
    __shared__ int s_any;
    if (threadIdx.x == 0) s_any = 0;
    __syncthreads();
    uint32_t v = 0;
    for (int i = 0; i < 16; ++i) {
        int idx = threadIdx.x * 16 + i;
        v |= edge_raw[2 * idx + 1];
    }
    if (v) atomicOr(&s_any, 1);
    __syncthreads();
    if (threadIdx.x == 0) *flag = (s_any == 0) ? 1 : 0;  // 1 => int64 layout
}

// ---------------- pass 1: bin edges into 196 dst-buckets -------------------
__global__ __launch_bounds__(256) void bucket_kernel(const void* edge_raw, const int* flag,
                                                     int* gcount, uint32_t* temp) {
    __shared__ int cnt[NBUCK];
    __shared__ int base[NBUCK];
    int t = threadIdx.x;
    if (t < NBUCK) cnt[t] = 0;
    __syncthreads();
    int is64 = *flag;
    int e0 = blockIdx.x * EPB;
    uint32_t val[16];
    int rb[16];
#pragma unroll
    for (int k = 0; k < 16; ++k) {
        int e = e0 + k * 256 + t;
        if (e < N_EDGES) {
            int s, d;
            if (is64) {
                const long long* p = (const long long*)edge_raw;
                s = (int)p[e]; d = (int)p[N_EDGES + e];
            } else {
                const int* p = (const int*)edge_raw;
                s = p[e]; d = p[N_EDGES + e];
            }
            int b = d >> 9;
            val[k] = ((uint32_t)s << 9) | (uint32_t)(d & 511);
            int r = atomicAdd(&cnt[b], 1);
            rb[k] = (b << 16) | r;
        } else {
            rb[k] = -1;
        }
    }
    __syncthreads();
    if (t < NBUCK) base[t] = atomicAdd(&gcount[t], cnt[t]);
    __syncthreads();
#pragma unroll
    for (int k = 0; k < 16; ++k) {
        if (rb[k] >= 0) {
            int b = rb[k] >> 16;
            int pos = base[b] + (rb[k] & 0xFFFF);
            if (pos < BCAP) temp[(size_t)b * BCAP + pos] = val[k];
        }
    }
}

// ---------------- scan of bucket counts ------------------------------------
__global__ void bscan_kernel(const int* gcount, int* bstart) {
    __shared__ int sh[256];
    int t = threadIdx.x;
    int v = (t < NBUCK) ? gcount[t] : 0;
    sh[t] = v;
    __syncthreads();
    for (int off = 1; off < 256; off <<= 1) {
        int a = (t >= off) ? sh[t - off] : 0;
        __syncthreads();
        sh[t] += a;
        __syncthreads();
    }
    if (t < NBUCK) bstart[t] = sh[t] - v;
    if (t == 0) bstart[NBUCK] = N_EDGES;
}

// ---------------- pass 2: per-bucket CSR build (no global atomics) ---------
__global__ __launch_bounds__(256) void build_kernel(const uint32_t* temp, const int* gcount,
                                                    const int* bstart, int* row_start,
                                                    float* dinv, int* ssort) {
    __shared__ int hist[512];
    __shared__ int sh[256];
    __shared__ int cur[512];
    int b = blockIdx.x;
    int t = threadIdx.x;
    int cnt = min(gcount[b], BCAP);
    int bs = bstart[b];
    const uint32_t* tp = temp + (size_t)b * BCAP;
    hist[t] = 0; hist[t + 256] = 0;
    __syncthreads();
    for (int i = t; i < cnt; i += 256) atomicAdd(&hist[tp[i] & 511], 1);
    __syncthreads();
    int d0 = hist[2 * t], d1 = hist[2 * t + 1];
    int ts = d0 + d1;
    sh[t] = ts;
    __syncthreads();
    for (int off = 1; off < 256; off <<= 1) {
        int a = (t >= off) ? sh[t - off] : 0;
        __syncthreads();
        sh[t] += a;
        __syncthreads();
    }
    int ex = sh[t] - ts;
    int node0 = b * 512 + 2 * t;
    cur[2 * t] = ex;
    cur[2 * t + 1] = ex + d0;
    if (node0 < N_NODES)     { row_start[node0]     = bs + ex;      dinv[node0]     = rsqrtf((float)(d0 + 1)); }
    if (node0 + 1 < N_NODES) { row_start[node0 + 1] = bs + ex + d0; dinv[node0 + 1] = rsqrtf((float)(d1 + 1)); }
    __syncthreads();
    for (int i = t; i < cnt; i += 256) {
        uint32_t v = tp[i];
        int pos = atomicAdd(&cur[v & 511], 1);
        ssort[bs + pos] = (int)(v >> 9);
    }
    if (b == 0 && t == 0) row_start[N_NODES] = N_EDGES;
}

// ---------------- GEMM1 (MFMA bf16 split-precision): y = dinv*(x@W1) -------
#define XST 260   // 256 + 4 floats pad; 1040 B row stride, 16B aligned
__global__ __launch_bounds__(128) void gemm1_kernel(const float* __restrict__ x,
                                                    const float* __restrict__ W1,
                                                    const float* __restrict__ dinv,
                                                    float* __restrict__ y) {
    __shared__ float xs[32 * XST];
    int t = threadIdx.x;
    int lane = t & 63;
    int wid = t >> 6;      // wave 0/1: rows 0-15 / 16-31
    int col = lane & 15;   // N index (and M row index for A-frag)
    int kg = lane >> 4;    // k-group 0..3
    frag8 whi[8], wlo[8];
#pragma unroll
    for (int s = 0; s < 8; ++s) {
#pragma unroll
        for (int j = 0; j < 8; ++j) {
            int k = s * 32 + kg * 8 + j;
            float wv = W1[k * HID + col];
            short h = f32_to_bf16_rn(wv);
            short l = f32_to_bf16_rn(wv - bf16_to_f32(h));
            whi[s][j] = h;
            wlo[s][j] = l;
        }
    }
    int v0 = blockIdx.x * 32;
    for (int i = t; i < 32 * 64; i += 128) {
        int r = i >> 6, c4 = i & 63;
        float4 val = ((const float4*)(x + (size_t)(v0 + r) * F_IN))[c4];
        *((float4*)(xs + r * XST + c4 * 4)) = val;
    }
    __syncthreads();
    const float* xrow = xs + (wid * 16 + col) * XST + kg * 8;
    f32x4 acc = {0.f, 0.f, 0.f, 0.f};
#pragma unroll
    for (int s = 0; s < 8; ++s) {
        float4 a = *((const float4*)(xrow + s * 32));
        float4 b = *((const float4*)(xrow + s * 32 + 4));
        float xv[8] = {a.x, a.y, a.z, a.w, b.x, b.y, b.z, b.w};
        frag8 ahi, alo;
#pragma unroll
        for (int j = 0; j < 8; ++j) {
            short h = f32_to_bf16_rn(xv[j]);
            short l = f32_to_bf16_rn(xv[j] - bf16_to_f32(h));
            ahi[j] = h; alo[j] = l;
        }
        acc = __builtin_amdgcn_mfma_f32_16x16x32_bf16(alo, whi[s], acc, 0, 0, 0);
        acc = __builtin_amdgcn_mfma_f32_16x16x32_bf16(ahi, wlo[s], acc, 0, 0, 0);
        acc = __builtin_amdgcn_mfma_f32_16x16x32_bf16(ahi, whi[s], acc, 0, 0, 0);
    }
#pragma unroll
    for (int r = 0; r < 4; ++r) {
        int gr = v0 + wid * 16 + kg * 4 + r;
        y[(size_t)gr * HID + col] = acc[r] * dinv[gr];
    }
}

// ---- gather+reduce: lane layout q = lane>>4 (quad), eg = lane&15 ----------
// returns this lane's quad of h = relu(dinv*(sum_in y + y_self) + b);
// every lane in a 16-lane group holds the same reduced quad.
__device__ inline float4 gather_reduce16(const float* __restrict__ y,
                                         const float* __restrict__ dinvp,
                                         const float* __restrict__ bias,
                                         const int* __restrict__ row_start,
                                         const int* __restrict__ ssort,
                                         int v, int q, int eg, float& dv_out) {
    int start = row_start[v];
    int end = row_start[v + 1];
    float4 acc = make_float4(0.f, 0.f, 0.f, 0.f);
    for (int base = start; base < end; base += 16) {
        int e = base + eg;
        if (e < end) {
            int s = ssort[e];
            float4 yv = *((const float4*)(y + (size_t)s * HID + q * 4));
            acc.x += yv.x; acc.y += yv.y; acc.z += yv.z; acc.w += yv.w;
        }
    }
#pragma unroll
    for (int m = 1; m < 16; m <<= 1) {
        acc.x += __shfl_xor(acc.x, m);
        acc.y += __shfl_xor(acc.y, m);
        acc.z += __shfl_xor(acc.z, m);
        acc.w += __shfl_xor(acc.w, m);
    }
    float4 self = *((const float4*)(y + (size_t)v * HID + q * 4));
    float dv = dinvp[v];
    float4 bv = *((const float4*)(bias + q * 4));
    float4 r;
    r.x = fmaxf(dv * (acc.x + self.x) + bv.x, 0.f);
    r.y = fmaxf(dv * (acc.y + self.y) + bv.y, 0.f);
    r.z = fmaxf(dv * (acc.z + self.z) + bv.z, 0.f);
    r.w = fmaxf(dv * (acc.w + self.w) + bv.w, 0.f);
    dv_out = dv;
    return r;
}

// ---------------- agg layer 1 fused with gemm2: y2 = dinv*(h1@W2) ----------
__global__ __launch_bounds__(256) void aggA_kernel(const float* __restrict__ y,
                                                   const float* __restrict__ dinvp,
                                                   const float* __restrict__ b1,
                                                   const float* __restrict__ W2,
                                                   const int* __restrict__ row_start,
                                                   const int* __restrict__ ssort,
                                                   float* __restrict__ y2) {
    int wid = (blockIdx.x * blockDim.x + threadIdx.x) >> 6;
    int lane = threadIdx.x & 63;
    int v = wid;
    if (v >= N_NODES) return;
    int q = lane >> 4;
    int eg = lane & 15;
    float dv;
    float4 r = gather_reduce16(y, dinvp, b1, row_start, ssort, v, q, eg, dv);
    // matvec: output col c = lane&15, partial over this lane's quad rows
    int c = lane & 15;
    int row0 = q * 4;
    float partial = r.x * W2[(row0 + 0) * 16 + c]
                  + r.y * W2[(row0 + 1) * 16 + c]
                  + r.z * W2[(row0 + 2) * 16 + c]
                  + r.w * W2[(row0 + 3) * 16 + c];
    partial += __shfl_xor(partial, 16);
    partial += __shfl_xor(partial, 32);
    if (lane < 16) y2[(size_t)v * HID + c] = dv * partial;
}

// ---------------- agg layer 2 fused with output + log_softmax --------------
__global__ __launch_bounds__(256) void aggB_kernel(const float* __restrict__ y,
                                                   const float* __restrict__ dinvp,
                                                   const float* __restrict__ b2,
                                                   const float* __restrict__ Wout,
                                                   const float* __restrict__ bout,
                                                   const int* __restrict__ row_start,
                                                   const int* __restrict__ ssort,
                                                   float* __restrict__ out) {
    int wid = (blockIdx.x * blockDim.x + threadIdx.x) >> 6;
    int lane = threadIdx.x & 63;
    int v = wid;
    if (v >= N_NODES) return;
    int q = lane >> 4;
    int eg = lane & 15;
    float dv;
    float4 r = gather_reduce16(y, dinvp, b2, row_start, ssort, v, q, eg, dv);
    int c = lane & 15;
    int row0 = q * 4;
    float partial = 0.f;
    if (c < NCLS) {
        partial = r.x * Wout[(row0 + 0) * NCLS + c]
                + r.y * Wout[(row0 + 1) * NCLS + c]
                + r.z * Wout[(row0 + 2) * NCLS + c]
                + r.w * Wout[(row0 + 3) * NCLS + c];
    }
    partial += __shfl_xor(partial, 16);
    partial += __shfl_xor(partial, 32);
    float lg = (c < NCLS) ? (partial + bout[c]) : -1e30f;
    float mx = lg;
#pragma unroll
    for (int m = 1; m < 16; m <<= 1) mx = fmaxf(mx, __shfl_xor(mx, m));
    float e = (c < NCLS) ? expf(lg - mx) : 0.f;
    float ssum = e;
#pragma unroll
    for (int m = 1; m < 16; m <<= 1) ssum += __shfl_xor(ssum, m);
    if (lane < NCLS) {
        float lse = mx + logf(ssum);
        out[(size_t)v * NCLS + c] = lg - lse;
    }
}

extern "C" void kernel_launch(void* const* d_in, const int* in_sizes, int n_in,
                              void* d_out, int out_size, void* d_ws, size_t ws_size,
                              hipStream_t stream) {
    const float* x    = (const float*)d_in[0];
    const void*  edge = d_in[1];
    const float* W1   = (const float*)d_in[2];
    const float* b1   = (const float*)d_in[3];
    const float* W2   = (const float*)d_in[4];
    const float* b2   = (const float*)d_in[5];
    const float* Wout = (const float*)d_in[6];
    const float* bout = (const float*)d_in[7];
    float* out = (float*)d_out;
    char* ws = (char*)d_ws;

    auto al = [](size_t v) { return (v + 255) & ~(size_t)255; };
    size_t o = 0;
    int*      flag      = (int*)(ws + o);      o = al(o + 4);
    int*      gcount    = (int*)(ws + o);      o = al(o + (size_t)NBUCK * 4);
    int*      bstart    = (int*)(ws + o);      o = al(o + (size_t)(NBUCK + 1) * 4);
    int*      row_start = (int*)(ws + o);      o = al(o + (size_t)(N_NODES + 1) * 4);
    float*    dinv      = (float*)(ws + o);    o = al(o + (size_t)N_NODES * 4);
    uint32_t* temp      = (uint32_t*)(ws + o); o = al(o + (size_t)NBUCK * BCAP * 4);
    int*      ssort     = (int*)(ws + o);      o = al(o + (size_t)N_EDGES * 4);
    float*    y1buf     = (float*)(ws + o);    o = al(o + (size_t)N_NODES * HID * 4);
    float*    y2buf     = (float*)(ws + o);    o = al(o + (size_t)N_NODES * HID * 4);

    hipMemsetAsync(gcount, 0, (size_t)NBUCK * 4, stream);
    detect_kernel<<<1, 256, 0, stream>>>((const uint32_t*)edge, flag);
    bucket_kernel<<<(N_EDGES + EPB - 1) / EPB, 256, 0, stream>>>(edge, flag, gcount, temp);
    bscan_kernel<<<1, 256, 0, stream>>>(gcount, bstart);
    build_kernel<<<NBUCK, 256, 0, stream>>>(temp, gcount, bstart, row_start, dinv, ssort);
    gemm1_kernel<<<N_NODES / 32, 128, 0, stream>>>(x, W1, dinv, y1buf);
    aggA_kernel<<<(N_NODES * 64) / 256, 256, 0, stream>>>(y1buf, dinv, b1, W2, row_start, ssort, y2buf);
    aggB_kernel<<<(N_NODES * 64) / 256, 256, 0, stream>>>(y2buf, dinv, b2, Wout, bout, row_start, ssort, out);
}

// Round 5
// 213.675 us; speedup vs baseline: 1.5150x; 1.0799x over previous
//
#include <hip/hip_runtime.h>
#include <stdint.h>

#define N_NODES 100000
#define N_EDGES 3200000
#define F_IN 256
#define HID 16
#define NCLS 7

#define NBUCK 196        // ceil(100000 / 512) buckets of 512 nodes (dst >> 9)
#define BCAP 20480       // capacity per bucket (avg 16384 -> 32 sigma headroom)
#define EPB 4096         // edges per block in bucket_kernel (16 per thread)

using frag8 = __attribute__((ext_vector_type(8))) short;
using f32x4 = __attribute__((ext_vector_type(4))) float;

__device__ inline short f32_to_bf16_rn(float f) {
    uint32_t u = __float_as_uint(f);
    uint32_t r = (u + 0x7FFF + ((u >> 16) & 1)) >> 16;
    return (short)r;
}
__device__ inline float bf16_to_f32(short s) {
    return __uint_as_float(((uint32_t)(uint16_t)s) << 16);
}

// ---------------- edge dtype detection (int64 vs int32) -------------------
__global__ void detect_kernel(const uint32_t* edge_raw, int* flag) {
    __shared__ int s_any;
    if (threadIdx.x == 0) s_any = 0;
    __syncthreads();
    uint32_t v = 0;
    for (int i = 0; i < 16; ++i) {
        int idx = threadIdx.x * 16 + i;
        v |= edge_raw[2 * idx + 1];
    }
    if (v) atomicOr(&s_any, 1);
    __syncthreads();
    if (threadIdx.x == 0) *flag = (s_any == 0) ? 1 : 0;  // 1 => int64 layout
}

// ---------------- pass 1: bin edges into 196 dst-buckets -------------------
__global__ __launch_bounds__(256) void bucket_kernel(const void* edge_raw, const int* flag,
                                                     int* gcount, uint32_t* temp) {
    __shared__ int cnt[NBUCK];
    __shared__ int base[NBUCK];
    int t = threadIdx.x;
    if (t < NBUCK) cnt[t] = 0;
    __syncthreads();
    int is64 = *flag;
    int e0 = blockIdx.x * EPB;
    uint32_t val[16];
    int rb[16];
#pragma unroll
    for (int k = 0; k < 16; ++k) {
        int e = e0 + k * 256 + t;
        if (e < N_EDGES) {
            int s, d;
            if (is64) {
                const long long* p = (const long long*)edge_raw;
                s = (int)p[e]; d = (int)p[N_EDGES + e];
            } else {
                const int* p = (const int*)edge_raw;
                s = p[e]; d = p[N_EDGES + e];
            }
            int b = d >> 9;
            val[k] = ((uint32_t)s << 9) | (uint32_t)(d & 511);
            int r = atomicAdd(&cnt[b], 1);
            rb[k] = (b << 16) | r;
        } else {
            rb[k] = -1;
        }
    }
    __syncthreads();
    if (t < NBUCK) base[t] = atomicAdd(&gcount[t], cnt[t]);
    __syncthreads();
#pragma unroll
    for (int k = 0; k < 16; ++k) {
        if (rb[k] >= 0) {
            int b = rb[k] >> 16;
            int pos = base[b] + (rb[k] & 0xFFFF);
            if (pos < BCAP) temp[(size_t)b * BCAP + pos] = val[k];
        }
    }
}

// ---------------- scan of bucket counts ------------------------------------
__global__ void bscan_kernel(const int* gcount, int* bstart) {
    __shared__ int sh[256];
    int t = threadIdx.x;
    int v = (t < NBUCK) ? gcount[t] : 0;
    sh[t] = v;
    __syncthreads();
    for (int off = 1; off < 256; off <<= 1) {
        int a = (t >= off) ? sh[t - off] : 0;
        __syncthreads();
        sh[t] += a;
        __syncthreads();
    }
    if (t < NBUCK) bstart[t] = sh[t] - v;
    if (t == 0) bstart[NBUCK] = N_EDGES;
}

// ---------------- pass 2: per-bucket CSR build (no global atomics) ---------
__global__ __launch_bounds__(256) void build_kernel(const uint32_t* temp, const int* gcount,
                                                    const int* bstart, int* row_start,
                                                    float* dinv, int* ssort) {
    __shared__ int hist[512];
    __shared__ int sh[256];
    __shared__ int cur[512];
    int b = blockIdx.x;
    int t = threadIdx.x;
    int cnt = min(gcount[b], BCAP);
    int bs = bstart[b];
    const uint32_t* tp = temp + (size_t)b * BCAP;
    hist[t] = 0; hist[t + 256] = 0;
    __syncthreads();
    for (int i = t; i < cnt; i += 256) atomicAdd(&hist[tp[i] & 511], 1);
    __syncthreads();
    int d0 = hist[2 * t], d1 = hist[2 * t + 1];
    int ts = d0 + d1;
    sh[t] = ts;
    __syncthreads();
    for (int off = 1; off < 256; off <<= 1) {
        int a = (t >= off) ? sh[t - off] : 0;
        __syncthreads();
        sh[t] += a;
        __syncthreads();
    }
    int ex = sh[t] - ts;
    int node0 = b * 512 + 2 * t;
    cur[2 * t] = ex;
    cur[2 * t + 1] = ex + d0;
    if (node0 < N_NODES)     { row_start[node0]     = bs + ex;      dinv[node0]     = rsqrtf((float)(d0 + 1)); }
    if (node0 + 1 < N_NODES) { row_start[node0 + 1] = bs + ex + d0; dinv[node0 + 1] = rsqrtf((float)(d1 + 1)); }
    __syncthreads();
    for (int i = t; i < cnt; i += 256) {
        uint32_t v = tp[i];
        int pos = atomicAdd(&cur[v & 511], 1);
        ssort[bs + pos] = (int)(v >> 9);
    }
    if (b == 0 && t == 0) row_start[N_NODES] = N_EDGES;
}

// ---------------- W1 fragment precompute (hi/lo bf16 split) ----------------
// Layout matches gemm1 lane mapping: lane l (kg=l>>4, col=l&15), step s,
// element j  ->  W1[(s*32 + kg*8 + j)*HID + col]
__global__ void wprep_kernel(const float* __restrict__ W1, frag8* __restrict__ whibuf,
                             frag8* __restrict__ wlobuf) {
    int l = threadIdx.x;  // 0..63
    int kg = l >> 4, col = l & 15;
#pragma unroll
    for (int s = 0; s < 8; ++s) {
        frag8 hi, lo;
#pragma unroll
        for (int j = 0; j < 8; ++j) {
            float wv = W1[(s * 32 + kg * 8 + j) * HID + col];
            short h = f32_to_bf16_rn(wv);
            short low = f32_to_bf16_rn(wv - bf16_to_f32(h));
            hi[j] = h; lo[j] = low;
        }
        whibuf[s * 64 + l] = hi;
        wlobuf[s * 64 + l] = lo;
    }
}

// ---------------- GEMM1 (MFMA, no LDS): y1 = bf16(dinv * (x @ W1)) ---------
__global__ __launch_bounds__(512) void gemm1_kernel(const float* __restrict__ x,
                                                    const frag8* __restrict__ whibuf,
                                                    const frag8* __restrict__ wlobuf,
                                                    const float* __restrict__ dinv,
                                                    ushort* __restrict__ y) {
    int t = threadIdx.x;
    int lane = t & 63;
    int w = t >> 6;        // wave 0..7, 16 rows each
    int col = lane & 15;   // N col of W1 / M row of A
    int kg = lane >> 4;    // k-group 0..3
    frag8 whi[8], wlo[8];
#pragma unroll
    for (int s = 0; s < 8; ++s) {
        whi[s] = whibuf[s * 64 + lane];
        wlo[s] = wlobuf[s * 64 + lane];
    }
    int v0 = blockIdx.x * 128 + w * 16;
    int arow = v0 + col;
    int arow_c = min(arow, N_NODES - 1);
    const float* xrow = x + (size_t)arow_c * F_IN + kg * 8;
    f32x4 acc = {0.f, 0.f, 0.f, 0.f};
#pragma unroll
    for (int s = 0; s < 8; ++s) {
        float4 a = *((const float4*)(xrow + s * 32));
        float4 b = *((const float4*)(xrow + s * 32 + 4));
        float xv[8] = {a.x, a.y, a.z, a.w, b.x, b.y, b.z, b.w};
        frag8 ahi, alo;
#pragma unroll
        for (int j = 0; j < 8; ++j) {
            short h = f32_to_bf16_rn(xv[j]);
            short l = f32_to_bf16_rn(xv[j] - bf16_to_f32(h));
            ahi[j] = h; alo[j] = l;
        }
        acc = __builtin_amdgcn_mfma_f32_16x16x32_bf16(alo, whi[s], acc, 0, 0, 0);
        acc = __builtin_amdgcn_mfma_f32_16x16x32_bf16(ahi, wlo[s], acc, 0, 0, 0);
        acc = __builtin_amdgcn_mfma_f32_16x16x32_bf16(ahi, whi[s], acc, 0, 0, 0);
    }
    // C layout: col = lane&15, tile row = kg*4 + r (m89-verified)
#pragma unroll
    for (int r = 0; r < 4; ++r) {
        int gr = v0 + kg * 4 + r;
        if (gr < N_NODES) {
            y[(size_t)gr * HID + col] = (ushort)f32_to_bf16_rn(acc[r] * dinv[gr]);
        }
    }
}

// ---- gather+reduce over bf16 table: q = lane>>4 (quad), eg = lane&15 ------
__device__ inline float4 gather_reduce16(const ushort* __restrict__ y,
                                         const float* __restrict__ dinvp,
                                         const float* __restrict__ bias,
                                         const int* __restrict__ row_start,
                                         const int* __restrict__ ssort,
                                         int v, int q, int eg, float& dv_out) {
    int start = row_start[v];
    int end = row_start[v + 1];
    float4 acc = make_float4(0.f, 0.f, 0.f, 0.f);
    for (int base = start; base < end; base += 16) {
        int e = base + eg;
        if (e < end) {
            int s = ssort[e];
            ushort4 yv = *((const ushort4*)(y + (size_t)s * HID + q * 4));
            acc.x += bf16_to_f32((short)yv.x);
            acc.y += bf16_to_f32((short)yv.y);
            acc.z += bf16_to_f32((short)yv.z);
            acc.w += bf16_to_f32((short)yv.w);
        }
    }
#pragma unroll
    for (int m = 1; m < 16; m <<= 1) {
        acc.x += __shfl_xor(acc.x, m);
        acc.y += __shfl_xor(acc.y, m);
        acc.z += __shfl_xor(acc.z, m);
        acc.w += __shfl_xor(acc.w, m);
    }
    ushort4 sv = *((const ushort4*)(y + (size_t)v * HID + q * 4));
    float dv = dinvp[v];
    float4 bv = *((const float4*)(bias + q * 4));
    float4 r;
    r.x = fmaxf(dv * (acc.x + bf16_to_f32((short)sv.x)) + bv.x, 0.f);
    r.y = fmaxf(dv * (acc.y + bf16_to_f32((short)sv.y)) + bv.y, 0.f);
    r.z = fmaxf(dv * (acc.z + bf16_to_f32((short)sv.z)) + bv.z, 0.f);
    r.w = fmaxf(dv * (acc.w + bf16_to_f32((short)sv.w)) + bv.w, 0.f);
    dv_out = dv;
    return r;
}

// ---------------- agg layer 1 fused with gemm2: y2 = bf16(dinv*(h1@W2)) ----
__global__ __launch_bounds__(256) void aggA_kernel(const ushort* __restrict__ y,
                                                   const float* __restrict__ dinvp,
                                                   const float* __restrict__ b1,
                                                   const float* __restrict__ W2,
                                                   const int* __restrict__ row_start,
                                                   const int* __restrict__ ssort,
                                                   ushort* __restrict__ y2) {
    int wid = (blockIdx.x * blockDim.x + threadIdx.x) >> 6;
    int lane = threadIdx.x & 63;
    int v = wid;
    if (v >= N_NODES) return;
    int q = lane >> 4;
    int eg = lane & 15;
    float dv;
    float4 r = gather_reduce16(y, dinvp, b1, row_start, ssort, v, q, eg, dv);
    int c = lane & 15;
    int row0 = q * 4;
    float partial = r.x * W2[(row0 + 0) * 16 + c]
                  + r.y * W2[(row0 + 1) * 16 + c]
                  + r.z * W2[(row0 + 2) * 16 + c]
                  + r.w * W2[(row0 + 3) * 16 + c];
    partial += __shfl_xor(partial, 16);
    partial += __shfl_xor(partial, 32);
    if (lane < 16) y2[(size_t)v * HID + c] = (ushort)f32_to_bf16_rn(dv * partial);
}

// ---------------- agg layer 2 fused with output + log_softmax --------------
__global__ __launch_bounds__(256) void aggB_kernel(const ushort* __restrict__ y,
                                                   const float* __restrict__ dinvp,
                                                   const float* __restrict__ b2,
                                                   const float* __restrict__ Wout,
                                                   const float* __restrict__ bout,
                                                   const int* __restrict__ row_start,
                                                   const int* __restrict__ ssort,
                                                   float* __restrict__ out) {
    int wid = (blockIdx.x * blockDim.x + threadIdx.x) >> 6;
    int lane = threadIdx.x & 63;
    int v = wid;
    if (v >= N_NODES) return;
    int q = lane >> 4;
    int eg = lane & 15;
    float dv;
    float4 r = gather_reduce16(y, dinvp, b2, row_start, ssort, v, q, eg, dv);
    int c = lane & 15;
    int row0 = q * 4;
    float partial = 0.f;
    if (c < NCLS) {
        partial = r.x * Wout[(row0 + 0) * NCLS + c]
                + r.y * Wout[(row0 + 1) * NCLS + c]
                + r.z * Wout[(row0 + 2) * NCLS + c]
                + r.w * Wout[(row0 + 3) * NCLS + c];
    }
    partial += __shfl_xor(partial, 16);
    partial += __shfl_xor(partial, 32);
    float lg = (c < NCLS) ? (partial + bout[c]) : -1e30f;
    float mx = lg;
#pragma unroll
    for (int m = 1; m < 16; m <<= 1) mx = fmaxf(mx, __shfl_xor(mx, m));
    float e = (c < NCLS) ? expf(lg - mx) : 0.f;
    float ssum = e;
#pragma unroll
    for (int m = 1; m < 16; m <<= 1) ssum += __shfl_xor(ssum, m);
    if (lane < NCLS) {
        float lse = mx + logf(ssum);
        out[(size_t)v * NCLS + c] = lg - lse;
    }
}

extern "C" void kernel_launch(void* const* d_in, const int* in_sizes, int n_in,
                              void* d_out, int out_size, void* d_ws, size_t ws_size,
                              hipStream_t stream) {
    const float* x    = (const float*)d_in[0];
    const void*  edge = d_in[1];
    const float* W1   = (const float*)d_in[2];
    const float* b1   = (const float*)d_in[3];
    const float* W2   = (const float*)d_in[4];
    const float* b2   = (const float*)d_in[5];
    const float* Wout = (const float*)d_in[6];
    const float* bout = (const float*)d_in[7];
    float* out = (float*)d_out;
    char* ws = (char*)d_ws;

    auto al = [](size_t v) { return (v + 255) & ~(size_t)255; };
    size_t o = 0;
    int*      flag      = (int*)(ws + o);      o = al(o + 4);
    int*      gcount    = (int*)(ws + o);      o = al(o + (size_t)NBUCK * 4);
    int*      bstart    = (int*)(ws + o);      o = al(o + (size_t)(NBUCK + 1) * 4);
    int*      row_start = (int*)(ws + o);      o = al(o + (size_t)(N_NODES + 1) * 4);
    float*    dinv      = (float*)(ws + o);    o = al(o + (size_t)N_NODES * 4);
    frag8*    whibuf    = (frag8*)(ws + o);    o = al(o + (size_t)8 * 64 * 16);
    frag8*    wlobuf    = (frag8*)(ws + o);    o = al(o + (size_t)8 * 64 * 16);
    uint32_t* temp      = (uint32_t*)(ws + o); o = al(o + (size_t)NBUCK * BCAP * 4);
    int*      ssort     = (int*)(ws + o);      o = al(o + (size_t)N_EDGES * 4);
    ushort*   y1buf     = (ushort*)(ws + o);   o = al(o + (size_t)N_NODES * HID * 2);
    ushort*   y2buf     = (ushort*)(ws + o);   o = al(o + (size_t)N_NODES * HID * 2);

    hipMemsetAsync(gcount, 0, (size_t)NBUCK * 4, stream);
    detect_kernel<<<1, 256, 0, stream>>>((const uint32_t*)edge, flag);
    bucket_kernel<<<(N_EDGES + EPB - 1) / EPB, 256, 0, stream>>>(edge, flag, gcount, temp);
    bscan_kernel<<<1, 256, 0, stream>>>(gcount, bstart);
    wprep_kernel<<<1, 64, 0, stream>>>(W1, whibuf, wlobuf);
    build_kernel<<<NBUCK, 256, 0, stream>>>(temp, gcount, bstart, row_start, dinv, ssort);
    gemm1_kernel<<<(N_NODES + 127) / 128, 512, 0, stream>>>(x, whibuf, wlobuf, dinv, y1buf);
    aggA_kernel<<<(N_NODES * 64) / 256, 256, 0, stream>>>(y1buf, dinv, b1, W2, row_start, ssort, y2buf);
    aggB_kernel<<<(N_NODES * 64) / 256, 256, 0, stream>>>(y2buf, dinv, b2, Wout, bout, row_start, ssort, out);
}

// Round 6
// 192.090 us; speedup vs baseline: 1.6853x; 1.1124x over previous
//
#include <hip/hip_runtime.h>
#include <stdint.h>

#define N_NODES 100000
#define N_EDGES 3200000
#define F_IN 256
#define HID 16
#define NCLS 7

#define NBUCK 391        // ceil(100000 / 256) buckets of 256 nodes (dst >> 8)
#define BCAP 9216        // capacity per bucket (avg 8184, sigma ~90 -> 11 sigma headroom)
#define EPB 8192         // edges per block in bucket_kernel (32 per thread)

using frag8 = __attribute__((ext_vector_type(8))) short;
using f32x4 = __attribute__((ext_vector_type(4))) float;

__device__ inline short f32_to_bf16_rn(float f) {
    uint32_t u = __float_as_uint(f);
    uint32_t r = (u + 0x7FFF + ((u >> 16) & 1)) >> 16;
    return (short)r;
}
__device__ inline float bf16_to_f32(short s) {
    return __uint_as_float(((uint32_t)(uint16_t)s) << 16);
}

// ---------------- pass 1: bin edges into 391 dst-buckets -------------------
// (edge dtype int64-vs-int32 detection inlined: sample 256 odd u32 words)
__global__ __launch_bounds__(256) void bucket_kernel(const void* edge_raw,
                                                     int* gcount, uint32_t* temp) {
    __shared__ int cnt[NBUCK];
    __shared__ int base[NBUCK];
    __shared__ int s_is32;
    int t = threadIdx.x;
    if (t == 0) s_is32 = 0;
    for (int i = t; i < NBUCK; i += 256) cnt[i] = 0;
    __syncthreads();
    // detect: int64 layout has all-zero high words (values < 2^32, non-negative)
    uint32_t probe = ((const uint32_t*)edge_raw)[2 * t + 1];
    if (probe) atomicOr(&s_is32, 1);
    __syncthreads();
    int is64 = (s_is32 == 0);
    int e0 = blockIdx.x * EPB;
    uint32_t val[32];
    int rb[32];  // (bucket << 16) | local_rank, or -1
#pragma unroll
    for (int k = 0; k < 32; ++k) {
        int e = e0 + k * 256 + t;
        if (e < N_EDGES) {
            int s, d;
            if (is64) {
                const long long* p = (const long long*)edge_raw;
                s = (int)p[e]; d = (int)p[N_EDGES + e];
            } else {
                const int* p = (const int*)edge_raw;
                s = p[e]; d = p[N_EDGES + e];
            }
            int b = d >> 8;
            val[k] = ((uint32_t)s << 8) | (uint32_t)(d & 255);
            int r = atomicAdd(&cnt[b], 1);
            rb[k] = (b << 16) | r;
        } else {
            rb[k] = -1;
        }
    }
    __syncthreads();
    for (int i = t; i < NBUCK; i += 256) {
        int c = cnt[i];
        base[i] = c ? atomicAdd(&gcount[i], c) : 0;
    }
    __syncthreads();
#pragma unroll
    for (int k = 0; k < 32; ++k) {
        if (rb[k] >= 0) {
            int b = rb[k] >> 16;
            int pos = base[b] + (rb[k] & 0xFFFF);
            if (pos < BCAP) temp[(size_t)b * BCAP + pos] = val[k];
        }
    }
}

// ---------------- aux: block 0 = bucket scan; block 1 = W1 fragment prep ---
__global__ __launch_bounds__(256) void aux_kernel(const int* gcount, int* bstart,
                                                  const float* __restrict__ W1,
                                                  frag8* __restrict__ whibuf,
                                                  frag8* __restrict__ wlobuf) {
    int t = threadIdx.x;
    if (blockIdx.x == 0) {
        __shared__ int sh[256];
        int i0 = 2 * t, i1 = 2 * t + 1;
        int v0 = (i0 < NBUCK) ? gcount[i0] : 0;
        int v1 = (i1 < NBUCK) ? gcount[i1] : 0;
        int ts = v0 + v1;
        sh[t] = ts;
        __syncthreads();
        for (int off = 1; off < 256; off <<= 1) {
            int a = (t >= off) ? sh[t - off] : 0;
            __syncthreads();
            sh[t] += a;
            __syncthreads();
        }
        int ex = sh[t] - ts;
        if (i0 < NBUCK) bstart[i0] = ex;
        if (i1 < NBUCK) bstart[i1] = ex + v0;
        if (t == 0) bstart[NBUCK] = N_EDGES;
    } else {
        if (t < 64) {
            int kg = t >> 4, col = t & 15;
#pragma unroll
            for (int s = 0; s < 8; ++s) {
                frag8 hi, lo;
#pragma unroll
                for (int j = 0; j < 8; ++j) {
                    float wv = W1[(s * 32 + kg * 8 + j) * HID + col];
                    short h = f32_to_bf16_rn(wv);
                    short low = f32_to_bf16_rn(wv - bf16_to_f32(h));
                    hi[j] = h; lo[j] = low;
                }
                whibuf[s * 64 + t] = hi;
                wlobuf[s * 64 + t] = lo;
            }
        }
    }
}

// ---------------- pass 2: per-bucket CSR build (no global atomics) ---------
__global__ __launch_bounds__(256) void build_kernel(const uint32_t* temp, const int* gcount,
                                                    const int* bstart, int* row_start,
                                                    float* dinv, int* ssort) {
    __shared__ int hist[256];
    __shared__ int sh[256];
    __shared__ int cur[256];
    int b = blockIdx.x;
    int t = threadIdx.x;
    int cnt = min(gcount[b], BCAP);
    int bs = bstart[b];
    const uint32_t* tp = temp + (size_t)b * BCAP;
    hist[t] = 0;
    __syncthreads();
    for (int i = t; i < cnt; i += 256) atomicAdd(&hist[tp[i] & 255], 1);
    __syncthreads();
    int dg = hist[t];
    sh[t] = dg;
    __syncthreads();
    for (int off = 1; off < 256; off <<= 1) {
        int a = (t >= off) ? sh[t - off] : 0;
        __syncthreads();
        sh[t] += a;
        __syncthreads();
    }
    int ex = sh[t] - dg;
    int node = b * 256 + t;
    cur[t] = ex;
    if (node < N_NODES) {
        row_start[node] = bs + ex;
        dinv[node] = rsqrtf((float)(dg + 1));
    }
    __syncthreads();
    for (int i = t; i < cnt; i += 256) {
        uint32_t v = tp[i];
        int pos = atomicAdd(&cur[v & 255], 1);
        ssort[bs + pos] = (int)(v >> 8);
    }
    if (b == 0 && t == 0) row_start[N_NODES] = N_EDGES;
}

// ---------------- GEMM1 (MFMA, no LDS): y1 = bf16(dinv * (x @ W1)) ---------
// W split hi/lo bf16 (2 MFMA); x rounded to bf16 once (error ~2^-9 rel).
__global__ __launch_bounds__(512) void gemm1_kernel(const float* __restrict__ x,
                                                    const frag8* __restrict__ whibuf,
                                                    const frag8* __restrict__ wlobuf,
                                                    const float* __restrict__ dinv,
                                                    ushort* __restrict__ y) {
    int t = threadIdx.x;
    int lane = t & 63;
    int w = t >> 6;        // wave 0..7, 16 rows each
    int col = lane & 15;   // N col of W1 / M row of A
    int kg = lane >> 4;    // k-group 0..3
    frag8 whi[8], wlo[8];
#pragma unroll
    for (int s = 0; s < 8; ++s) {
        whi[s] = whibuf[s * 64 + lane];
        wlo[s] = wlobuf[s * 64 + lane];
    }
    int v0 = blockIdx.x * 128 + w * 16;
    int arow = v0 + col;
    int arow_c = min(arow, N_NODES - 1);
    const float* xrow = x + (size_t)arow_c * F_IN + kg * 8;
    f32x4 acc = {0.f, 0.f, 0.f, 0.f};
#pragma unroll
    for (int s = 0; s < 8; ++s) {
        float4 a = *((const float4*)(xrow + s * 32));
        float4 b = *((const float4*)(xrow + s * 32 + 4));
        frag8 ahi;
        ahi[0] = f32_to_bf16_rn(a.x); ahi[1] = f32_to_bf16_rn(a.y);
        ahi[2] = f32_to_bf16_rn(a.z); ahi[3] = f32_to_bf16_rn(a.w);
        ahi[4] = f32_to_bf16_rn(b.x); ahi[5] = f32_to_bf16_rn(b.y);
        ahi[6] = f32_to_bf16_rn(b.z); ahi[7] = f32_to_bf16_rn(b.w);
        acc = __builtin_amdgcn_mfma_f32_16x16x32_bf16(ahi, wlo[s], acc, 0, 0, 0);
        acc = __builtin_amdgcn_mfma_f32_16x16x32_bf16(ahi, whi[s], acc, 0, 0, 0);
    }
    // C layout: col = lane&15, tile row = kg*4 + r (m89-verified)
#pragma unroll
    for (int r = 0; r < 4; ++r) {
        int gr = v0 + kg * 4 + r;
        if (gr < N_NODES) {
            y[(size_t)gr * HID + col] = (ushort)f32_to_bf16_rn(acc[r] * dinv[gr]);
        }
    }
}

// ---- gather+reduce over bf16 table: q = lane>>4 (quad), eg = lane&15 ------
__device__ inline float4 gather_reduce16(const ushort* __restrict__ y,
                                         const float* __restrict__ dinvp,
                                         const float* __restrict__ bias,
                                         const int* __restrict__ row_start,
                                         const int* __restrict__ ssort,
                                         int v, int q, int eg, float& dv_out) {
    int start = row_start[v];
    int end = row_start[v + 1];
    float4 acc = make_float4(0.f, 0.f, 0.f, 0.f);
    for (int base = start; base < end; base += 16) {
        int e = base + eg;
        if (e < end) {
            int s = ssort[e];
            ushort4 yv = *((const ushort4*)(y + (size_t)s * HID + q * 4));
            acc.x += bf16_to_f32((short)yv.x);
            acc.y += bf16_to_f32((short)yv.y);
            acc.z += bf16_to_f32((short)yv.z);
            acc.w += bf16_to_f32((short)yv.w);
        }
    }
#pragma unroll
    for (int m = 1; m < 16; m <<= 1) {
        acc.x += __shfl_xor(acc.x, m);
        acc.y += __shfl_xor(acc.y, m);
        acc.z += __shfl_xor(acc.z, m);
        acc.w += __shfl_xor(acc.w, m);
    }
    ushort4 sv = *((const ushort4*)(y + (size_t)v * HID + q * 4));
    float dv = dinvp[v];
    float4 bv = *((const float4*)(bias + q * 4));
    float4 r;
    r.x = fmaxf(dv * (acc.x + bf16_to_f32((short)sv.x)) + bv.x, 0.f);
    r.y = fmaxf(dv * (acc.y + bf16_to_f32((short)sv.y)) + bv.y, 0.f);
    r.z = fmaxf(dv * (acc.z + bf16_to_f32((short)sv.z)) + bv.z, 0.f);
    r.w = fmaxf(dv * (acc.w + bf16_to_f32((short)sv.w)) + bv.w, 0.f);
    dv_out = dv;
    return r;
}

// ---------------- agg layer 1 fused with gemm2: y2 = bf16(dinv*(h1@W2)) ----
__global__ __launch_bounds__(256) void aggA_kernel(const ushort* __restrict__ y,
                                                   const float* __restrict__ dinvp,
                                                   const float* __restrict__ b1,
                                                   const float* __restrict__ W2,
                                                   const int* __restrict__ row_start,
                                                   const int* __restrict__ ssort,
                                                   ushort* __restrict__ y2) {
    int wid = (blockIdx.x * blockDim.x + threadIdx.x) >> 6;
    int lane = threadIdx.x & 63;
    int v = wid;
    if (v >= N_NODES) return;
    int q = lane >> 4;
    int eg = lane & 15;
    float dv;
    float4 r = gather_reduce16(y, dinvp, b1, row_start, ssort, v, q, eg, dv);
    int c = lane & 15;
    int row0 = q * 4;
    float partial = r.x * W2[(row0 + 0) * 16 + c]
                  + r.y * W2[(row0 + 1) * 16 + c]
                  + r.z * W2[(row0 + 2) * 16 + c]
                  + r.w * W2[(row0 + 3) * 16 + c];
    partial += __shfl_xor(partial, 16);
    partial += __shfl_xor(partial, 32);
    if (lane < 16) y2[(size_t)v * HID + c] = (ushort)f32_to_bf16_rn(dv * partial);
}

// ---------------- agg layer 2 fused with output + log_softmax --------------
__global__ __launch_bounds__(256) void aggB_kernel(const ushort* __restrict__ y,
                                                   const float* __restrict__ dinvp,
                                                   const float* __restrict__ b2,
                                                   const float* __restrict__ Wout,
                                                   const float* __restrict__ bout,
                                                   const int* __restrict__ row_start,
                                                   const int* __restrict__ ssort,
                                                   float* __restrict__ out) {
    int wid = (blockIdx.x * blockDim.x + threadIdx.x) >> 6;
    int lane = threadIdx.x & 63;
    int v = wid;
    if (v >= N_NODES) return;
    int q = lane >> 4;
    int eg = lane & 15;
    float dv;
    float4 r = gather_reduce16(y, dinvp, b2, row_start, ssort, v, q, eg, dv);
    int c = lane & 15;
    int row0 = q * 4;
    float partial = 0.f;
    if (c < NCLS) {
        partial = r.x * Wout[(row0 + 0) * NCLS + c]
                + r.y * Wout[(row0 + 1) * NCLS + c]
                + r.z * Wout[(row0 + 2) * NCLS + c]
                + r.w * Wout[(row0 + 3) * NCLS + c];
    }
    partial += __shfl_xor(partial, 16);
    partial += __shfl_xor(partial, 32);
    float lg = (c < NCLS) ? (partial + bout[c]) : -1e30f;
    float mx = lg;
#pragma unroll
    for (int m = 1; m < 16; m <<= 1) mx = fmaxf(mx, __shfl_xor(mx, m));
    float e = (c < NCLS) ? expf(lg - mx) : 0.f;
    float ssum = e;
#pragma unroll
    for (int m = 1; m < 16; m <<= 1) ssum += __shfl_xor(ssum, m);
    if (lane < NCLS) {
        float lse = mx + logf(ssum);
        out[(size_t)v * NCLS + c] = lg - lse;
    }
}

extern "C" void kernel_launch(void* const* d_in, const int* in_sizes, int n_in,
                              void* d_out, int out_size, void* d_ws, size_t ws_size,
                              hipStream_t stream) {
    const float* x    = (const float*)d_in[0];
    const void*  edge = d_in[1];
    const float* W1   = (const float*)d_in[2];
    const float* b1   = (const float*)d_in[3];
    const float* W2   = (const float*)d_in[4];
    const float* b2   = (const float*)d_in[5];
    const float* Wout = (const float*)d_in[6];
    const float* bout = (const float*)d_in[7];
    float* out = (float*)d_out;
    char* ws = (char*)d_ws;

    auto al = [](size_t v) { return (v + 255) & ~(size_t)255; };
    size_t o = 0;
    int*      gcount    = (int*)(ws + o);      o = al(o + (size_t)NBUCK * 4);
    int*      bstart    = (int*)(ws + o);      o = al(o + (size_t)(NBUCK + 1) * 4);
    int*      row_start = (int*)(ws + o);      o = al(o + (size_t)(N_NODES + 1) * 4);
    float*    dinv      = (float*)(ws + o);    o = al(o + (size_t)N_NODES * 4);
    frag8*    whibuf    = (frag8*)(ws + o);    o = al(o + (size_t)8 * 64 * 16);
    frag8*    wlobuf    = (frag8*)(ws + o);    o = al(o + (size_t)8 * 64 * 16);
    uint32_t* temp      = (uint32_t*)(ws + o); o = al(o + (size_t)NBUCK * BCAP * 4);
    int*      ssort     = (int*)(ws + o);      o = al(o + (size_t)N_EDGES * 4);
    ushort*   y1buf     = (ushort*)(ws + o);   o = al(o + (size_t)N_NODES * HID * 2);
    ushort*   y2buf     = (ushort*)(ws + o);   o = al(o + (size_t)N_NODES * HID * 2);

    hipMemsetAsync(gcount, 0, (size_t)NBUCK * 4, stream);
    bucket_kernel<<<(N_EDGES + EPB - 1) / EPB, 256, 0, stream>>>(edge, gcount, temp);
    aux_kernel<<<2, 256, 0, stream>>>(gcount, bstart, W1, whibuf, wlobuf);
    build_kernel<<<NBUCK, 256, 0, stream>>>(temp, gcount, bstart, row_start, dinv, ssort);
    gemm1_kernel<<<(N_NODES + 127) / 128, 512, 0, stream>>>(x, whibuf, wlobuf, dinv, y1buf);
    aggA_kernel<<<(N_NODES * 64) / 256, 256, 0, stream>>>(y1buf, dinv, b1, W2, row_start, ssort, y2buf);
    aggB_kernel<<<(N_NODES * 64) / 256, 256, 0, stream>>>(y2buf, dinv, b2, Wout, bout, row_start, ssort, out);
}

// Round 7
// 187.333 us; speedup vs baseline: 1.7281x; 1.0254x over previous
//
#include <hip/hip_runtime.h>
#include <stdint.h>

#define N_NODES 100000
#define N_EDGES 3200000
#define F_IN 256
#define HID 16
#define NCLS 7

#define NBUCK 391        // ceil(100000 / 256) buckets of 256 nodes (dst >> 8)
#define BCAP 9216        // capacity per bucket (avg 8184 -> ample headroom)
#define EPB 4096         // edges per block in bucket_kernel (16 per thread)

using frag8 = __attribute__((ext_vector_type(8))) short;
using f32x4 = __attribute__((ext_vector_type(4))) float;

__device__ inline short f32_to_bf16_rn(float f) {
    uint32_t u = __float_as_uint(f);
    uint32_t r = (u + 0x7FFF + ((u >> 16) & 1)) >> 16;
    return (short)r;
}
__device__ inline float bf16_to_f32(short s) {
    return __uint_as_float(((uint32_t)(uint16_t)s) << 16);
}

// ---------------- pass 1: bin edges into 391 dst-buckets -------------------
// LDS-regrouped so global writes are bucket-contiguous runs (full lines).
// Block 0 additionally prepares W1 hi/lo bf16 fragments (side job).
__global__ __launch_bounds__(256) void bucket_kernel(const void* edge_raw,
                                                     int* gcount, uint32_t* temp,
                                                     const float* __restrict__ W1,
                                                     frag8* __restrict__ whibuf,
                                                     frag8* __restrict__ wlobuf) {
    __shared__ int cnt[NBUCK];
    __shared__ int lofs[NBUCK + 1];
    __shared__ int gbase[NBUCK];
    __shared__ int sh[256];
    __shared__ uint32_t buf2[EPB];
    __shared__ uint16_t bucket_of[EPB];
    __shared__ int s_is32;
    int t = threadIdx.x;
    if (t == 0) s_is32 = 0;
    for (int i = t; i < NBUCK; i += 256) cnt[i] = 0;
    __syncthreads();
    // detect: int64 layout has all-zero high words (values < 2^32, non-negative)
    uint32_t probe = ((const uint32_t*)edge_raw)[2 * t + 1];
    if (probe) atomicOr(&s_is32, 1);
    __syncthreads();
    int is64 = (s_is32 == 0);
    int e0 = blockIdx.x * EPB;
    int total = min(EPB, N_EDGES - e0);
    uint32_t val[16];
    int bk[16], rk[16];
#pragma unroll
    for (int k = 0; k < 16; ++k) {
        int e = e0 + k * 256 + t;
        if (e < N_EDGES) {
            int s, d;
            if (is64) {
                const long long* p = (const long long*)edge_raw;
                s = (int)p[e]; d = (int)p[N_EDGES + e];
            } else {
                const int* p = (const int*)edge_raw;
                s = p[e]; d = p[N_EDGES + e];
            }
            int b = d >> 8;
            val[k] = ((uint32_t)s << 8) | (uint32_t)(d & 255);
            bk[k] = b;
            rk[k] = atomicAdd(&cnt[b], 1);
        } else {
            bk[k] = -1;
        }
    }
    __syncthreads();
    // exclusive scan of cnt -> lofs (2 adjacent entries per thread)
    {
        int i0 = 2 * t, i1 = 2 * t + 1;
        int v0 = (i0 < NBUCK) ? cnt[i0] : 0;
        int v1 = (i1 < NBUCK) ? cnt[i1] : 0;
        int ts = v0 + v1;
        sh[t] = ts;
        __syncthreads();
        for (int off = 1; off < 256; off <<= 1) {
            int a = (t >= off) ? sh[t - off] : 0;
            __syncthreads();
            sh[t] += a;
            __syncthreads();
        }
        int ex = sh[t] - ts;
        if (i0 < NBUCK) lofs[i0] = ex;
        if (i1 < NBUCK) lofs[i1] = ex + v0;
    }
    __syncthreads();
    // place into LDS grouped by bucket (rank unique per (block,bucket))
#pragma unroll
    for (int k = 0; k < 16; ++k) {
        if (bk[k] >= 0) {
            int p = lofs[bk[k]] + rk[k];
            buf2[p] = val[k];
            bucket_of[p] = (uint16_t)bk[k];
        }
    }
    // global reservation per bucket
    for (int i = t; i < NBUCK; i += 256) {
        int c = cnt[i];
        gbase[i] = c ? atomicAdd(&gcount[i], c) : 0;
    }
    __syncthreads();
    // coalesced write-out: consecutive i are bucket-grouped runs
    for (int i = t; i < total; i += 256) {
        int b = bucket_of[i];
        int pos = gbase[b] + (i - lofs[b]);
        if (pos < BCAP) temp[(size_t)b * BCAP + pos] = buf2[i];
    }
    // side job: W1 fragment prep (block 0, lanes 0-63)
    if (blockIdx.x == 0 && t < 64) {
        int kg = t >> 4, col = t & 15;
#pragma unroll
        for (int s = 0; s < 8; ++s) {
            frag8 hi, lo;
#pragma unroll
            for (int j = 0; j < 8; ++j) {
                float wv = W1[(s * 32 + kg * 8 + j) * HID + col];
                short h = f32_to_bf16_rn(wv);
                short low = f32_to_bf16_rn(wv - bf16_to_f32(h));
                hi[j] = h; lo[j] = low;
            }
            whibuf[s * 64 + t] = hi;
            wlobuf[s * 64 + t] = lo;
        }
    }
}

// ---------------- pass 2: per-bucket CSR build (self-computed bstart) ------
__global__ __launch_bounds__(256) void build_kernel(const uint32_t* temp, const int* gcount,
                                                    int* row_start, float* dinv, int* ssort) {
    __shared__ int hist[256];
    __shared__ int sh[256];
    __shared__ int cur[256];
    __shared__ int wsum[4];
    int b = blockIdx.x;
    int t = threadIdx.x;
    // bstart = sum of gcount[i] for i < b (gcount is L2-hot, 391 ints)
    int g0 = (t < NBUCK && t < b) ? gcount[t] : 0;
    int g1 = (t + 256 < NBUCK && t + 256 < b) ? gcount[t + 256] : 0;
    int part = g0 + g1;
#pragma unroll
    for (int m = 1; m < 64; m <<= 1) part += __shfl_xor(part, m);
    if ((t & 63) == 0) wsum[t >> 6] = part;
    int cnt = min(gcount[b], BCAP);
    const uint32_t* tp = temp + (size_t)b * BCAP;
    hist[t] = 0;
    __syncthreads();
    int bs = wsum[0] + wsum[1] + wsum[2] + wsum[3];
    for (int i = t; i < cnt; i += 256) atomicAdd(&hist[tp[i] & 255], 1);
    __syncthreads();
    int dg = hist[t];
    sh[t] = dg;
    __syncthreads();
    for (int off = 1; off < 256; off <<= 1) {
        int a = (t >= off) ? sh[t - off] : 0;
        __syncthreads();
        sh[t] += a;
        __syncthreads();
    }
    int ex = sh[t] - dg;
    int node = b * 256 + t;
    cur[t] = ex;
    if (node < N_NODES) {
        row_start[node] = bs + ex;
        dinv[node] = rsqrtf((float)(dg + 1));
    }
    __syncthreads();
    for (int i = t; i < cnt; i += 256) {
        uint32_t v = tp[i];
        int pos = atomicAdd(&cur[v & 255], 1);
        ssort[bs + pos] = (int)(v >> 8);
    }
    if (b == 0 && t == 0) row_start[N_NODES] = N_EDGES;
}

// ---------------- GEMM1 (MFMA, no LDS): y1 = bf16(dinv * (x @ W1)) ---------
__global__ __launch_bounds__(512) void gemm1_kernel(const float* __restrict__ x,
                                                    const frag8* __restrict__ whibuf,
                                                    const frag8* __restrict__ wlobuf,
                                                    const float* __restrict__ dinv,
                                                    ushort* __restrict__ y) {
    int t = threadIdx.x;
    int lane = t & 63;
    int w = t >> 6;        // wave 0..7, 16 rows each
    int col = lane & 15;   // N col of W1 / M row of A
    int kg = lane >> 4;    // k-group 0..3
    frag8 whi[8], wlo[8];
#pragma unroll
    for (int s = 0; s < 8; ++s) {
        whi[s] = whibuf[s * 64 + lane];
        wlo[s] = wlobuf[s * 64 + lane];
    }
    int v0 = blockIdx.x * 128 + w * 16;
    int arow = v0 + col;
    int arow_c = min(arow, N_NODES - 1);
    const float* xrow = x + (size_t)arow_c * F_IN + kg * 8;
    f32x4 acc = {0.f, 0.f, 0.f, 0.f};
#pragma unroll
    for (int s = 0; s < 8; ++s) {
        float4 a = *((const float4*)(xrow + s * 32));
        float4 b = *((const float4*)(xrow + s * 32 + 4));
        frag8 ahi;
        ahi[0] = f32_to_bf16_rn(a.x); ahi[1] = f32_to_bf16_rn(a.y);
        ahi[2] = f32_to_bf16_rn(a.z); ahi[3] = f32_to_bf16_rn(a.w);
        ahi[4] = f32_to_bf16_rn(b.x); ahi[5] = f32_to_bf16_rn(b.y);
        ahi[6] = f32_to_bf16_rn(b.z); ahi[7] = f32_to_bf16_rn(b.w);
        acc = __builtin_amdgcn_mfma_f32_16x16x32_bf16(ahi, wlo[s], acc, 0, 0, 0);
        acc = __builtin_amdgcn_mfma_f32_16x16x32_bf16(ahi, whi[s], acc, 0, 0, 0);
    }
#pragma unroll
    for (int r = 0; r < 4; ++r) {
        int gr = v0 + kg * 4 + r;
        if (gr < N_NODES) {
            y[(size_t)gr * HID + col] = (ushort)f32_to_bf16_rn(acc[r] * dinv[gr]);
        }
    }
}

// ---- gather+reduce over bf16 table: q = lane>>4 (quad), eg = lane&15 ------
__device__ inline float4 gather_reduce16(const ushort* __restrict__ y,
                                         const float* __restrict__ dinvp,
                                         const float* __restrict__ bias,
                                         const int* __restrict__ row_start,
                                         const int* __restrict__ ssort,
                                         int v, int q, int eg, float& dv_out) {
    int start = row_start[v];
    int end = row_start[v + 1];
    float4 acc = make_float4(0.f, 0.f, 0.f, 0.f);
    for (int base = start; base < end; base += 16) {
        int e = base + eg;
        if (e < end) {
            int s = ssort[e];
            ushort4 yv = *((const ushort4*)(y + (size_t)s * HID + q * 4));
            acc.x += bf16_to_f32((short)yv.x);
            acc.y += bf16_to_f32((short)yv.y);
            acc.z += bf16_to_f32((short)yv.z);
            acc.w += bf16_to_f32((short)yv.w);
        }
    }
#pragma unroll
    for (int m = 1; m < 16; m <<= 1) {
        acc.x += __shfl_xor(acc.x, m);
        acc.y += __shfl_xor(acc.y, m);
        acc.z += __shfl_xor(acc.z, m);
        acc.w += __shfl_xor(acc.w, m);
    }
    ushort4 sv = *((const ushort4*)(y + (size_t)v * HID + q * 4));
    float dv = dinvp[v];
    float4 bv = *((const float4*)(bias + q * 4));
    float4 r;
    r.x = fmaxf(dv * (acc.x + bf16_to_f32((short)sv.x)) + bv.x, 0.f);
    r.y = fmaxf(dv * (acc.y + bf16_to_f32((short)sv.y)) + bv.y, 0.f);
    r.z = fmaxf(dv * (acc.z + bf16_to_f32((short)sv.z)) + bv.z, 0.f);
    r.w = fmaxf(dv * (acc.w + bf16_to_f32((short)sv.w)) + bv.w, 0.f);
    dv_out = dv;
    return r;
}

// ---------------- agg layer 1 fused with gemm2: y2 = bf16(dinv*(h1@W2)) ----
__global__ __launch_bounds__(256) void aggA_kernel(const ushort* __restrict__ y,
                                                   const float* __restrict__ dinvp,
                                                   const float* __restrict__ b1,
                                                   const float* __restrict__ W2,
                                                   const int* __restrict__ row_start,
                                                   const int* __restrict__ ssort,
                                                   ushort* __restrict__ y2) {
    int wid = (blockIdx.x * blockDim.x + threadIdx.x) >> 6;
    int lane = threadIdx.x & 63;
    int v = wid;
    if (v >= N_NODES) return;
    int q = lane >> 4;
    int eg = lane & 15;
    float dv;
    float4 r = gather_reduce16(y, dinvp, b1, row_start, ssort, v, q, eg, dv);
    int c = lane & 15;
    int row0 = q * 4;
    float partial = r.x * W2[(row0 + 0) * 16 + c]
                  + r.y * W2[(row0 + 1) * 16 + c]
                  + r.z * W2[(row0 + 2) * 16 + c]
                  + r.w * W2[(row0 + 3) * 16 + c];
    partial += __shfl_xor(partial, 16);
    partial += __shfl_xor(partial, 32);
    if (lane < 16) y2[(size_t)v * HID + c] = (ushort)f32_to_bf16_rn(dv * partial);
}

// ---------------- agg layer 2 fused with output + log_softmax --------------
__global__ __launch_bounds__(256) void aggB_kernel(const ushort* __restrict__ y,
                                                   const float* __restrict__ dinvp,
                                                   const float* __restrict__ b2,
                                                   const float* __restrict__ Wout,
                                                   const float* __restrict__ bout,
                                                   const int* __restrict__ row_start,
                                                   const int* __restrict__ ssort,
                                                   float* __restrict__ out) {
    int wid = (blockIdx.x * blockDim.x + threadIdx.x) >> 6;
    int lane = threadIdx.x & 63;
    int v = wid;
    if (v >= N_NODES) return;
    int q = lane >> 4;
    int eg = lane & 15;
    float dv;
    float4 r = gather_reduce16(y, dinvp, b2, row_start, ssort, v, q, eg, dv);
    int c = lane & 15;
    int row0 = q * 4;
    float partial = 0.f;
    if (c < NCLS) {
        partial = r.x * Wout[(row0 + 0) * NCLS + c]
                + r.y * Wout[(row0 + 1) * NCLS + c]
                + r.z * Wout[(row0 + 2) * NCLS + c]
                + r.w * Wout[(row0 + 3) * NCLS + c];
    }
    partial += __shfl_xor(partial, 16);
    partial += __shfl_xor(partial, 32);
    float lg = (c < NCLS) ? (partial + bout[c]) : -1e30f;
    float mx = lg;
#pragma unroll
    for (int m = 1; m < 16; m <<= 1) mx = fmaxf(mx, __shfl_xor(mx, m));
    float e = (c < NCLS) ? expf(lg - mx) : 0.f;
    float ssum = e;
#pragma unroll
    for (int m = 1; m < 16; m <<= 1) ssum += __shfl_xor(ssum, m);
    if (lane < NCLS) {
        float lse = mx + logf(ssum);
        out[(size_t)v * NCLS + c] = lg - lse;
    }
}

extern "C" void kernel_launch(void* const* d_in, const int* in_sizes, int n_in,
                              void* d_out, int out_size, void* d_ws, size_t ws_size,
                              hipStream_t stream) {
    const float* x    = (const float*)d_in[0];
    const void*  edge = d_in[1];
    const float* W1   = (const float*)d_in[2];
    const float* b1   = (const float*)d_in[3];
    const float* W2   = (const float*)d_in[4];
    const float* b2   = (const float*)d_in[5];
    const float* Wout = (const float*)d_in[6];
    const float* bout = (const float*)d_in[7];
    float* out = (float*)d_out;
    char* ws = (char*)d_ws;

    auto al = [](size_t v) { return (v + 255) & ~(size_t)255; };
    size_t o = 0;
    int*      gcount    = (int*)(ws + o);      o = al(o + (size_t)NBUCK * 4);
    int*      row_start = (int*)(ws + o);      o = al(o + (size_t)(N_NODES + 1) * 4);
    float*    dinv      = (float*)(ws + o);    o = al(o + (size_t)N_NODES * 4);
    frag8*    whibuf    = (frag8*)(ws + o);    o = al(o + (size_t)8 * 64 * 16);
    frag8*    wlobuf    = (frag8*)(ws + o);    o = al(o + (size_t)8 * 64 * 16);
    uint32_t* temp      = (uint32_t*)(ws + o); o = al(o + (size_t)NBUCK * BCAP * 4);
    int*      ssort     = (int*)(ws + o);      o = al(o + (size_t)N_EDGES * 4);
    ushort*   y1buf     = (ushort*)(ws + o);   o = al(o + (size_t)N_NODES * HID * 2);
    ushort*   y2buf     = (ushort*)(ws + o);   o = al(o + (size_t)N_NODES * HID * 2);

    hipMemsetAsync(gcount, 0, (size_t)NBUCK * 4, stream);
    bucket_kernel<<<(N_EDGES + EPB - 1) / EPB, 256, 0, stream>>>(edge, gcount, temp, W1, whibuf, wlobuf);
    build_kernel<<<NBUCK, 256, 0, stream>>>(temp, gcount, row_start, dinv, ssort);
    gemm1_kernel<<<(N_NODES + 127) / 128, 512, 0, stream>>>(x, whibuf, wlobuf, dinv, y1buf);
    aggA_kernel<<<(N_NODES * 64) / 256, 256, 0, stream>>>(y1buf, dinv, b1, W2, row_start, ssort, y2buf);
    aggB_kernel<<<(N_NODES * 64) / 256, 256, 0, stream>>>(y2buf, dinv, b2, Wout, bout, row_start, ssort, out);
}

// Round 8
// 179.564 us; speedup vs baseline: 1.8029x; 1.0433x over previous
//
#include <hip/hip_runtime.h>
#include <hip/hip_bf16.h>
#include <stdint.h>

#define N_NODES 100000
#define N_EDGES 3200000
#define F_IN 256
#define HID 16
#define NCLS 7

#define NBUCK 391        // ceil(100000 / 256) buckets of 256 nodes (dst >> 8)
#define BCAP 9216        // capacity per bucket (avg 8184 -> ample headroom)
#define EPB 4096         // edges per block in bucket_kernel (16 per thread)

using frag8 = __attribute__((ext_vector_type(8))) short;
using f32x4 = __attribute__((ext_vector_type(4))) float;

// exact split helper (W prep only)
__device__ inline short f32_to_bf16_rn(float f) {
    uint32_t u = __float_as_uint(f);
    uint32_t r = (u + 0x7FFF + ((u >> 16) & 1)) >> 16;
    return (short)r;
}
__device__ inline float bf16_to_f32(short s) {
    return __uint_as_float(((uint32_t)(uint16_t)s) << 16);
}
// native convert (compiler emits v_cvt_pk_bf16_f32 for adjacent pairs)
__device__ inline short f32_bf16_native(float f) {
    __hip_bfloat16 h = __float2bfloat16(f);
    union { __hip_bfloat16 b; unsigned short u; } cv;
    cv.b = h;
    return (short)cv.u;
}

// ---------------- pass 1: bin edges into 391 dst-buckets -------------------
// LDS-regrouped so global writes are bucket-contiguous runs (full lines).
// Block 0 additionally prepares W1 hi/lo bf16 fragments (side job).
__global__ __launch_bounds__(256) void bucket_kernel(const void* edge_raw,
                                                     int* gcount, uint32_t* temp,
                                                     const float* __restrict__ W1,
                                                     frag8* __restrict__ whibuf,
                                                     frag8* __restrict__ wlobuf) {
    __shared__ int cnt[NBUCK];
    __shared__ int lofs[NBUCK + 1];
    __shared__ int gbase[NBUCK];
    __shared__ int sh[256];
    __shared__ uint32_t buf2[EPB];
    __shared__ uint16_t bucket_of[EPB];
    __shared__ int s_is32;
    int t = threadIdx.x;
    if (t == 0) s_is32 = 0;
    for (int i = t; i < NBUCK; i += 256) cnt[i] = 0;
    __syncthreads();
    uint32_t probe = ((const uint32_t*)edge_raw)[2 * t + 1];
    if (probe) atomicOr(&s_is32, 1);
    __syncthreads();
    int is64 = (s_is32 == 0);
    int e0 = blockIdx.x * EPB;
    int total = min(EPB, N_EDGES - e0);
    uint32_t val[16];
    int bk[16], rk[16];
#pragma unroll
    for (int k = 0; k < 16; ++k) {
        int e = e0 + k * 256 + t;
        if (e < N_EDGES) {
            int s, d;
            if (is64) {
                const long long* p = (const long long*)edge_raw;
                s = (int)p[e]; d = (int)p[N_EDGES + e];
            } else {
                const int* p = (const int*)edge_raw;
                s = p[e]; d = p[N_EDGES + e];
            }
            int b = d >> 8;
            val[k] = ((uint32_t)s << 8) | (uint32_t)(d & 255);
            bk[k] = b;
            rk[k] = atomicAdd(&cnt[b], 1);
        } else {
            bk[k] = -1;
        }
    }
    __syncthreads();
    {
        int i0 = 2 * t, i1 = 2 * t + 1;
        int v0 = (i0 < NBUCK) ? cnt[i0] : 0;
        int v1 = (i1 < NBUCK) ? cnt[i1] : 0;
        int ts = v0 + v1;
        sh[t] = ts;
        __syncthreads();
        for (int off = 1; off < 256; off <<= 1) {
            int a = (t >= off) ? sh[t - off] : 0;
            __syncthreads();
            sh[t] += a;
            __syncthreads();
        }
        int ex = sh[t] - ts;
        if (i0 < NBUCK) lofs[i0] = ex;
        if (i1 < NBUCK) lofs[i1] = ex + v0;
    }
    __syncthreads();
#pragma unroll
    for (int k = 0; k < 16; ++k) {
        if (bk[k] >= 0) {
            int p = lofs[bk[k]] + rk[k];
            buf2[p] = val[k];
            bucket_of[p] = (uint16_t)bk[k];
        }
    }
    for (int i = t; i < NBUCK; i += 256) {
        int c = cnt[i];
        gbase[i] = c ? atomicAdd(&gcount[i], c) : 0;
    }
    __syncthreads();
    for (int i = t; i < total; i += 256) {
        int b = bucket_of[i];
        int pos = gbase[b] + (i - lofs[b]);
        if (pos < BCAP) temp[(size_t)b * BCAP + pos] = buf2[i];
    }
    if (blockIdx.x == 0 && t < 64) {
        int kg = t >> 4, col = t & 15;
#pragma unroll
        for (int s = 0; s < 8; ++s) {
            frag8 hi, lo;
#pragma unroll
            for (int j = 0; j < 8; ++j) {
                float wv = W1[(s * 32 + kg * 8 + j) * HID + col];
                short h = f32_to_bf16_rn(wv);
                short low = f32_to_bf16_rn(wv - bf16_to_f32(h));
                hi[j] = h; lo[j] = low;
            }
            whibuf[s * 64 + t] = hi;
            wlobuf[s * 64 + t] = lo;
        }
    }
}

// ---------------- pass 2: per-bucket CSR build, LDS-staged coalesced out ---
__global__ __launch_bounds__(256) void build_kernel(const uint32_t* temp, const int* gcount,
                                                    int* row_start, float* dinv, int* ssort) {
    __shared__ int hist[256];
    __shared__ int sh[256];
    __shared__ int cur[256];
    __shared__ int wsum[4];
    __shared__ int sbuf[BCAP];
    int b = blockIdx.x;
    int t = threadIdx.x;
    // bstart = sum of gcount[i] for i < b (gcount is L2-hot, 391 ints)
    int g0 = (t < NBUCK && t < b) ? gcount[t] : 0;
    int g1 = (t + 256 < NBUCK && t + 256 < b) ? gcount[t + 256] : 0;
    int part = g0 + g1;
#pragma unroll
    for (int m = 1; m < 64; m <<= 1) part += __shfl_xor(part, m);
    if ((t & 63) == 0) wsum[t >> 6] = part;
    int cnt = min(gcount[b], BCAP);
    const uint32_t* tp = temp + (size_t)b * BCAP;
    hist[t] = 0;
    __syncthreads();
    int bs = wsum[0] + wsum[1] + wsum[2] + wsum[3];
    for (int i = t; i < cnt; i += 256) atomicAdd(&hist[tp[i] & 255], 1);
    __syncthreads();
    int dg = hist[t];
    sh[t] = dg;
    __syncthreads();
    for (int off = 1; off < 256; off <<= 1) {
        int a = (t >= off) ? sh[t - off] : 0;
        __syncthreads();
        sh[t] += a;
        __syncthreads();
    }
    int ex = sh[t] - dg;
    int node = b * 256 + t;
    cur[t] = ex;
    if (node < N_NODES) {
        row_start[node] = bs + ex;
        dinv[node] = rsqrtf((float)(dg + 1));
    }
    __syncthreads();
    // permute into LDS (random LDS writes), then coalesced global write-out
    for (int i = t; i < cnt; i += 256) {
        uint32_t v = tp[i];
        int pos = atomicAdd(&cur[v & 255], 1);
        sbuf[pos] = (int)(v >> 8);
    }
    __syncthreads();
    for (int i = t; i < cnt; i += 256) ssort[bs + i] = sbuf[i];
    if (b == 0 && t == 0) row_start[N_NODES] = N_EDGES;
}

// ---------------- GEMM1 (MFMA, no LDS): y1 = bf16(dinv * (x @ W1)) ---------
__global__ __launch_bounds__(512) void gemm1_kernel(const float* __restrict__ x,
                                                    const frag8* __restrict__ whibuf,
                                                    const frag8* __restrict__ wlobuf,
                                                    const float* __restrict__ dinv,
                                                    ushort* __restrict__ y) {
    int t = threadIdx.x;
    int lane = t & 63;
    int w = t >> 6;        // wave 0..7, 16 rows each
    int col = lane & 15;   // N col of W1 / M row of A
    int kg = lane >> 4;    // k-group 0..3
    frag8 whi[8], wlo[8];
#pragma unroll
    for (int s = 0; s < 8; ++s) {
        whi[s] = whibuf[s * 64 + lane];
        wlo[s] = wlobuf[s * 64 + lane];
    }
    int v0 = blockIdx.x * 128 + w * 16;
    int arow = v0 + col;
    int arow_c = min(arow, N_NODES - 1);
    const float* xrow = x + (size_t)arow_c * F_IN + kg * 8;
    f32x4 acc = {0.f, 0.f, 0.f, 0.f};
#pragma unroll
    for (int s = 0; s < 8; ++s) {
        float4 a = *((const float4*)(xrow + s * 32));
        float4 b = *((const float4*)(xrow + s * 32 + 4));
        frag8 ahi;
        ahi[0] = f32_bf16_native(a.x); ahi[1] = f32_bf16_native(a.y);
        ahi[2] = f32_bf16_native(a.z); ahi[3] = f32_bf16_native(a.w);
        ahi[4] = f32_bf16_native(b.x); ahi[5] = f32_bf16_native(b.y);
        ahi[6] = f32_bf16_native(b.z); ahi[7] = f32_bf16_native(b.w);
        acc = __builtin_amdgcn_mfma_f32_16x16x32_bf16(ahi, wlo[s], acc, 0, 0, 0);
        acc = __builtin_amdgcn_mfma_f32_16x16x32_bf16(ahi, whi[s], acc, 0, 0, 0);
    }
#pragma unroll
    for (int r = 0; r < 4; ++r) {
        int gr = v0 + kg * 4 + r;
        if (gr < N_NODES) {
            y[(size_t)gr * HID + col] = (ushort)f32_bf16_native(acc[r] * dinv[gr]);
        }
    }
}

// ---- gather+reduce over bf16 table: q = lane>>4 (quad), eg = lane&15 ------
__device__ inline float4 gather_reduce16(const ushort* __restrict__ y,
                                         const float* __restrict__ dinvp,
                                         const float* __restrict__ bias,
                                         const int* __restrict__ row_start,
                                         const int* __restrict__ ssort,
                                         int v, int q, int eg, float& dv_out) {
    int start = row_start[v];
    int end = row_start[v + 1];
    float4 acc = make_float4(0.f, 0.f, 0.f, 0.f);
    for (int base = start; base < end; base += 16) {
        int e = base + eg;
        if (e < end) {
            int s = ssort[e];
            ushort4 yv = *((const ushort4*)(y + (size_t)s * HID + q * 4));
            acc.x += bf16_to_f32((short)yv.x);
            acc.y += bf16_to_f32((short)yv.y);
            acc.z += bf16_to_f32((short)yv.z);
            acc.w += bf16_to_f32((short)yv.w);
        }
    }
#pragma unroll
    for (int m = 1; m < 16; m <<= 1) {
        acc.x += __shfl_xor(acc.x, m);
        acc.y += __shfl_xor(acc.y, m);
        acc.z += __shfl_xor(acc.z, m);
        acc.w += __shfl_xor(acc.w, m);
    }
    ushort4 sv = *((const ushort4*)(y + (size_t)v * HID + q * 4));
    float dv = dinvp[v];
    float4 bv = *((const float4*)(bias + q * 4));
    float4 r;
    r.x = fmaxf(dv * (acc.x + bf16_to_f32((short)sv.x)) + bv.x, 0.f);
    r.y = fmaxf(dv * (acc.y + bf16_to_f32((short)sv.y)) + bv.y, 0.f);
    r.z = fmaxf(dv * (acc.z + bf16_to_f32((short)sv.z)) + bv.z, 0.f);
    r.w = fmaxf(dv * (acc.w + bf16_to_f32((short)sv.w)) + bv.w, 0.f);
    dv_out = dv;
    return r;
}

// ---------------- agg layer 1 fused with gemm2: y2 = bf16(dinv*(h1@W2)) ----
__global__ __launch_bounds__(256) void aggA_kernel(const ushort* __restrict__ y,
                                                   const float* __restrict__ dinvp,
                                                   const float* __restrict__ b1,
                                                   const float* __restrict__ W2,
                                                   const int* __restrict__ row_start,
                                                   const int* __restrict__ ssort,
                                                   ushort* __restrict__ y2) {
    int wid = (blockIdx.x * blockDim.x + threadIdx.x) >> 6;
    int lane = threadIdx.x & 63;
    int v = wid;
    if (v >= N_NODES) return;
    int q = lane >> 4;
    int eg = lane & 15;
    float dv;
    float4 r = gather_reduce16(y, dinvp, b1, row_start, ssort, v, q, eg, dv);
    int c = lane & 15;
    int row0 = q * 4;
    float partial = r.x * W2[(row0 + 0) * 16 + c]
                  + r.y * W2[(row0 + 1) * 16 + c]
                  + r.z * W2[(row0 + 2) * 16 + c]
                  + r.w * W2[(row0 + 3) * 16 + c];
    partial += __shfl_xor(partial, 16);
    partial += __shfl_xor(partial, 32);
    if (lane < 16) y2[(size_t)v * HID + c] = (ushort)f32_bf16_native(dv * partial);
}

// ---------------- agg layer 2 fused with output + log_softmax --------------
__global__ __launch_bounds__(256) void aggB_kernel(const ushort* __restrict__ y,
                                                   const float* __restrict__ dinvp,
                                                   const float* __restrict__ b2,
                                                   const float* __restrict__ Wout,
                                                   const float* __restrict__ bout,
                                                   const int* __restrict__ row_start,
                                                   const int* __restrict__ ssort,
                                                   float* __restrict__ out) {
    int wid = (blockIdx.x * blockDim.x + threadIdx.x) >> 6;
    int lane = threadIdx.x & 63;
    int v = wid;
    if (v >= N_NODES) return;
    int q = lane >> 4;
    int eg = lane & 15;
    float dv;
    float4 r = gather_reduce16(y, dinvp, b2, row_start, ssort, v, q, eg, dv);
    int c = lane & 15;
    int row0 = q * 4;
    float partial = 0.f;
    if (c < NCLS) {
        partial = r.x * Wout[(row0 + 0) * NCLS + c]
                + r.y * Wout[(row0 + 1) * NCLS + c]
                + r.z * Wout[(row0 + 2) * NCLS + c]
                + r.w * Wout[(row0 + 3) * NCLS + c];
    }
    partial += __shfl_xor(partial, 16);
    partial += __shfl_xor(partial, 32);
    float lg = (c < NCLS) ? (partial + bout[c]) : -1e30f;
    float mx = lg;
#pragma unroll
    for (int m = 1; m < 16; m <<= 1) mx = fmaxf(mx, __shfl_xor(mx, m));
    float e = (c < NCLS) ? expf(lg - mx) : 0.f;
    float ssum = e;
#pragma unroll
    for (int m = 1; m < 16; m <<= 1) ssum += __shfl_xor(ssum, m);
    if (lane < NCLS) {
        float lse = mx + logf(ssum);
        out[(size_t)v * NCLS + c] = lg - lse;
    }
}

extern "C" void kernel_launch(void* const* d_in, const int* in_sizes, int n_in,
                              void* d_out, int out_size, void* d_ws, size_t ws_size,
                              hipStream_t stream) {
    const float* x    = (const float*)d_in[0];
    const void*  edge = d_in[1];
    const float* W1   = (const float*)d_in[2];
    const float* b1   = (const float*)d_in[3];
    const float* W2   = (const float*)d_in[4];
    const float* b2   = (const float*)d_in[5];
    const float* Wout = (const float*)d_in[6];
    const float* bout = (const float*)d_in[7];
    float* out = (float*)d_out;
    char* ws = (char*)d_ws;

    auto al = [](size_t v) { return (v + 255) & ~(size_t)255; };
    size_t o = 0;
    int*      gcount    = (int*)(ws + o);      o = al(o + (size_t)NBUCK * 4);
    int*      row_start = (int*)(ws + o);      o = al(o + (size_t)(N_NODES + 1) * 4);
    float*    dinv      = (float*)(ws + o);    o = al(o + (size_t)N_NODES * 4);
    frag8*    whibuf    = (frag8*)(ws + o);    o = al(o + (size_t)8 * 64 * 16);
    frag8*    wlobuf    = (frag8*)(ws + o);    o = al(o + (size_t)8 * 64 * 16);
    uint32_t* temp      = (uint32_t*)(ws + o); o = al(o + (size_t)NBUCK * BCAP * 4);
    int*      ssort     = (int*)(ws + o);      o = al(o + (size_t)N_EDGES * 4);
    ushort*   y1buf     = (ushort*)(ws + o);   o = al(o + (size_t)N_NODES * HID * 2);
    ushort*   y2buf     = (ushort*)(ws + o);   o = al(o + (size_t)N_NODES * HID * 2);

    hipMemsetAsync(gcount, 0, (size_t)NBUCK * 4, stream);
    bucket_kernel<<<(N_EDGES + EPB - 1) / EPB, 256, 0, stream>>>(edge, gcount, temp, W1, whibuf, wlobuf);
    build_kernel<<<NBUCK, 256, 0, stream>>>(temp, gcount, row_start, dinv, ssort);
    gemm1_kernel<<<(N_NODES + 127) / 128, 512, 0, stream>>>(x, whibuf, wlobuf, dinv, y1buf);
    aggA_kernel<<<(N_NODES * 64) / 256, 256, 0, stream>>>(y1buf, dinv, b1, W2, row_start, ssort, y2buf);
    aggB_kernel<<<(N_NODES * 64) / 256, 256, 0, stream>>>(y2buf, dinv, b2, Wout, bout, row_start, ssort, out);
}

// Round 9
// 172.394 us; speedup vs baseline: 1.8778x; 1.0416x over previous
//
#include <hip/hip_runtime.h>
#include <hip/hip_bf16.h>
#include <stdint.h>

#define N_NODES 100000
#define N_EDGES 3200000
#define F_IN 256
#define HID 16
#define NCLS 7

#define NBUCK 391        // ceil(100000 / 256) buckets of 256 nodes (dst >> 8)
#define BCAP 9216        // capacity per bucket (avg 8184 -> ample headroom)
#define EPB 4096         // edges per block in bucket_kernel (16 per thread)

using frag8 = __attribute__((ext_vector_type(8))) short;
using f32x4 = __attribute__((ext_vector_type(4))) float;

// exact split helper (W prep only)
__device__ inline short f32_to_bf16_rn(float f) {
    uint32_t u = __float_as_uint(f);
    uint32_t r = (u + 0x7FFF + ((u >> 16) & 1)) >> 16;
    return (short)r;
}
__device__ inline float bf16_to_f32(short s) {
    return __uint_as_float(((uint32_t)(uint16_t)s) << 16);
}
// native convert (compiler emits v_cvt_pk_bf16_f32 for adjacent pairs)
__device__ inline short f32_bf16_native(float f) {
    __hip_bfloat16 h = __float2bfloat16(f);
    union { __hip_bfloat16 b; unsigned short u; } cv;
    cv.b = h;
    return (short)cv.u;
}

// ---------------- pass 1: bin edges into 391 dst-buckets -------------------
__global__ __launch_bounds__(256) void bucket_kernel(const void* edge_raw,
                                                     int* gcount, uint32_t* temp,
                                                     const float* __restrict__ W1,
                                                     frag8* __restrict__ whibuf,
                                                     frag8* __restrict__ wlobuf) {
    __shared__ int cnt[NBUCK];
    __shared__ int lofs[NBUCK + 1];
    __shared__ int gbase[NBUCK];
    __shared__ int sh[256];
    __shared__ uint32_t buf2[EPB];
    __shared__ uint16_t bucket_of[EPB];
    __shared__ int s_is32;
    int t = threadIdx.x;
    if (t == 0) s_is32 = 0;
    for (int i = t; i < NBUCK; i += 256) cnt[i] = 0;
    __syncthreads();
    uint32_t probe = ((const uint32_t*)edge_raw)[2 * t + 1];
    if (probe) atomicOr(&s_is32, 1);
    __syncthreads();
    int is64 = (s_is32 == 0);
    int e0 = blockIdx.x * EPB;
    int total = min(EPB, N_EDGES - e0);
    uint32_t val[16];
    int bk[16], rk[16];
#pragma unroll
    for (int k = 0; k < 16; ++k) {
        int e = e0 + k * 256 + t;
        if (e < N_EDGES) {
            int s, d;
            if (is64) {
                const long long* p = (const long long*)edge_raw;
                s = (int)p[e]; d = (int)p[N_EDGES + e];
            } else {
                const int* p = (const int*)edge_raw;
                s = p[e]; d = p[N_EDGES + e];
            }
            int b = d >> 8;
            val[k] = ((uint32_t)s << 8) | (uint32_t)(d & 255);
            bk[k] = b;
            rk[k] = atomicAdd(&cnt[b], 1);
        } else {
            bk[k] = -1;
        }
    }
    __syncthreads();
    {
        int i0 = 2 * t, i1 = 2 * t + 1;
        int v0 = (i0 < NBUCK) ? cnt[i0] : 0;
        int v1 = (i1 < NBUCK) ? cnt[i1] : 0;
        int ts = v0 + v1;
        sh[t] = ts;
        __syncthreads();
        for (int off = 1; off < 256; off <<= 1) {
            int a = (t >= off) ? sh[t - off] : 0;
            __syncthreads();
            sh[t] += a;
            __syncthreads();
        }
        int ex = sh[t] - ts;
        if (i0 < NBUCK) lofs[i0] = ex;
        if (i1 < NBUCK) lofs[i1] = ex + v0;
    }
    __syncthreads();
#pragma unroll
    for (int k = 0; k < 16; ++k) {
        if (bk[k] >= 0) {
            int p = lofs[bk[k]] + rk[k];
            buf2[p] = val[k];
            bucket_of[p] = (uint16_t)bk[k];
        }
    }
    for (int i = t; i < NBUCK; i += 256) {
        int c = cnt[i];
        gbase[i] = c ? atomicAdd(&gcount[i], c) : 0;
    }
    __syncthreads();
    for (int i = t; i < total; i += 256) {
        int b = bucket_of[i];
        int pos = gbase[b] + (i - lofs[b]);
        if (pos < BCAP) temp[(size_t)b * BCAP + pos] = buf2[i];
    }
    if (blockIdx.x == 0 && t < 64) {
        int kg = t >> 4, col = t & 15;
#pragma unroll
        for (int s = 0; s < 8; ++s) {
            frag8 hi, lo;
#pragma unroll
            for (int j = 0; j < 8; ++j) {
                float wv = W1[(s * 32 + kg * 8 + j) * HID + col];
                short h = f32_to_bf16_rn(wv);
                short low = f32_to_bf16_rn(wv - bf16_to_f32(h));
                hi[j] = h; lo[j] = low;
            }
            whibuf[s * 64 + t] = hi;
            wlobuf[s * 64 + t] = lo;
        }
    }
}

// ---------------- pass 2: per-bucket CSR build, LDS-staged coalesced out ---
__global__ __launch_bounds__(256) void build_kernel(const uint32_t* temp, const int* gcount,
                                                    int* row_start, float* dinv, int* ssort) {
    __shared__ int hist[256];
    __shared__ int sh[256];
    __shared__ int cur[256];
    __shared__ int wsum[4];
    __shared__ int sbuf[BCAP];
    int b = blockIdx.x;
    int t = threadIdx.x;
    int g0 = (t < NBUCK && t < b) ? gcount[t] : 0;
    int g1 = (t + 256 < NBUCK && t + 256 < b) ? gcount[t + 256] : 0;
    int part = g0 + g1;
#pragma unroll
    for (int m = 1; m < 64; m <<= 1) part += __shfl_xor(part, m);
    if ((t & 63) == 0) wsum[t >> 6] = part;
    int cnt = min(gcount[b], BCAP);
    const uint32_t* tp = temp + (size_t)b * BCAP;
    hist[t] = 0;
    __syncthreads();
    int bs = wsum[0] + wsum[1] + wsum[2] + wsum[3];
    for (int i = t; i < cnt; i += 256) atomicAdd(&hist[tp[i] & 255], 1);
    __syncthreads();
    int dg = hist[t];
    sh[t] = dg;
    __syncthreads();
    for (int off = 1; off < 256; off <<= 1) {
        int a = (t >= off) ? sh[t - off] : 0;
        __syncthreads();
        sh[t] += a;
        __syncthreads();
    }
    int ex = sh[t] - dg;
    int node = b * 256 + t;
    cur[t] = ex;
    if (node < N_NODES) {
        row_start[node] = bs + ex;
        dinv[node] = rsqrtf((float)(dg + 1));
    }
    __syncthreads();
    for (int i = t; i < cnt; i += 256) {
        uint32_t v = tp[i];
        int pos = atomicAdd(&cur[v & 255], 1);
        sbuf[pos] = (int)(v >> 8);
    }
    __syncthreads();
    for (int i = t; i < cnt; i += 256) ssort[bs + i] = sbuf[i];
    if (b == 0 && t == 0) row_start[N_NODES] = N_EDGES;
}

// ---------------- GEMM1 (MFMA, no LDS): y1 = bf16(dinv * (x @ W1)) ---------
__global__ __launch_bounds__(512) void gemm1_kernel(const float* __restrict__ x,
                                                    const frag8* __restrict__ whibuf,
                                                    const frag8* __restrict__ wlobuf,
                                                    const float* __restrict__ dinv,
                                                    ushort* __restrict__ y) {
    int t = threadIdx.x;
    int lane = t & 63;
    int w = t >> 6;
    int col = lane & 15;
    int kg = lane >> 4;
    frag8 whi[8], wlo[8];
#pragma unroll
    for (int s = 0; s < 8; ++s) {
        whi[s] = whibuf[s * 64 + lane];
        wlo[s] = wlobuf[s * 64 + lane];
    }
    int v0 = blockIdx.x * 128 + w * 16;
    int arow = v0 + col;
    int arow_c = min(arow, N_NODES - 1);
    const float* xrow = x + (size_t)arow_c * F_IN + kg * 8;
    f32x4 acc = {0.f, 0.f, 0.f, 0.f};
#pragma unroll
    for (int s = 0; s < 8; ++s) {
        float4 a = *((const float4*)(xrow + s * 32));
        float4 b = *((const float4*)(xrow + s * 32 + 4));
        frag8 ahi;
        ahi[0] = f32_bf16_native(a.x); ahi[1] = f32_bf16_native(a.y);
        ahi[2] = f32_bf16_native(a.z); ahi[3] = f32_bf16_native(a.w);
        ahi[4] = f32_bf16_native(b.x); ahi[5] = f32_bf16_native(b.y);
        ahi[6] = f32_bf16_native(b.z); ahi[7] = f32_bf16_native(b.w);
        acc = __builtin_amdgcn_mfma_f32_16x16x32_bf16(ahi, wlo[s], acc, 0, 0, 0);
        acc = __builtin_amdgcn_mfma_f32_16x16x32_bf16(ahi, whi[s], acc, 0, 0, 0);
    }
#pragma unroll
    for (int r = 0; r < 4; ++r) {
        int gr = v0 + kg * 4 + r;
        if (gr < N_NODES) {
            y[(size_t)gr * HID + col] = (ushort)f32_bf16_native(acc[r] * dinv[gr]);
        }
    }
}

// ---- gather+reduce, 2-edge unrolled (32 edges/iter) for MLP ---------------
__device__ inline float4 gather_reduce16(const ushort* __restrict__ y,
                                         const float* __restrict__ dinvp,
                                         const float* __restrict__ bias,
                                         const int* __restrict__ row_start,
                                         const int* __restrict__ ssort,
                                         int v, int q, int eg, float& dv_out) {
    int start = row_start[v];
    int end = row_start[v + 1];
    float4 acc = make_float4(0.f, 0.f, 0.f, 0.f);
    int base = start;
    // main loop: 32 edges/iter, lane eg handles edges base+2eg, base+2eg+1
    for (; base + 32 <= end; base += 32) {
        int2 ss = *((const int2*)(ssort + base + 2 * eg));
        ushort4 y0 = *((const ushort4*)(y + (size_t)ss.x * HID + q * 4));
        ushort4 y1 = *((const ushort4*)(y + (size_t)ss.y * HID + q * 4));
        acc.x += bf16_to_f32((short)y0.x) + bf16_to_f32((short)y1.x);
        acc.y += bf16_to_f32((short)y0.y) + bf16_to_f32((short)y1.y);
        acc.z += bf16_to_f32((short)y0.z) + bf16_to_f32((short)y1.z);
        acc.w += bf16_to_f32((short)y0.w) + bf16_to_f32((short)y1.w);
    }
    // tail: up to 31 edges, 16-wide masked
    for (; base < end; base += 16) {
        int e = base + eg;
        if (e < end) {
            int s = ssort[e];
            ushort4 yv = *((const ushort4*)(y + (size_t)s * HID + q * 4));
            acc.x += bf16_to_f32((short)yv.x);
            acc.y += bf16_to_f32((short)yv.y);
            acc.z += bf16_to_f32((short)yv.z);
            acc.w += bf16_to_f32((short)yv.w);
        }
    }
#pragma unroll
    for (int m = 1; m < 16; m <<= 1) {
        acc.x += __shfl_xor(acc.x, m);
        acc.y += __shfl_xor(acc.y, m);
        acc.z += __shfl_xor(acc.z, m);
        acc.w += __shfl_xor(acc.w, m);
    }
    ushort4 sv = *((const ushort4*)(y + (size_t)v * HID + q * 4));
    float dv = dinvp[v];
    float4 bv = *((const float4*)(bias + q * 4));
    float4 r;
    r.x = fmaxf(dv * (acc.x + bf16_to_f32((short)sv.x)) + bv.x, 0.f);
    r.y = fmaxf(dv * (acc.y + bf16_to_f32((short)sv.y)) + bv.y, 0.f);
    r.z = fmaxf(dv * (acc.z + bf16_to_f32((short)sv.z)) + bv.z, 0.f);
    r.w = fmaxf(dv * (acc.w + bf16_to_f32((short)sv.w)) + bv.w, 0.f);
    dv_out = dv;
    return r;
}

// ---------------- agg layer 1 fused with gemm2: y2 = bf16(dinv*(h1@W2)) ----
__global__ __launch_bounds__(256) void aggA_kernel(const ushort* __restrict__ y,
                                                   const float* __restrict__ dinvp,
                                                   const float* __restrict__ b1,
                                                   const float* __restrict__ W2,
                                                   const int* __restrict__ row_start,
                                                   const int* __restrict__ ssort,
                                                   ushort* __restrict__ y2) {
    int wid = (blockIdx.x * blockDim.x + threadIdx.x) >> 6;
    int lane = threadIdx.x & 63;
    int v = wid;
    if (v >= N_NODES) return;
    int q = lane >> 4;
    int eg = lane & 15;
    float dv;
    float4 r = gather_reduce16(y, dinvp, b1, row_start, ssort, v, q, eg, dv);
    int c = lane & 15;
    int row0 = q * 4;
    float partial = r.x * W2[(row0 + 0) * 16 + c]
                  + r.y * W2[(row0 + 1) * 16 + c]
                  + r.z * W2[(row0 + 2) * 16 + c]
                  + r.w * W2[(row0 + 3) * 16 + c];
    partial += __shfl_xor(partial, 16);
    partial += __shfl_xor(partial, 32);
    if (lane < 16) y2[(size_t)v * HID + c] = (ushort)f32_bf16_native(dv * partial);
}

// ---------------- agg layer 2 fused with output + log_softmax --------------
__global__ __launch_bounds__(256) void aggB_kernel(const ushort* __restrict__ y,
                                                   const float* __restrict__ dinvp,
                                                   const float* __restrict__ b2,
                                                   const float* __restrict__ Wout,
                                                   const float* __restrict__ bout,
                                                   const int* __restrict__ row_start,
                                                   const int* __restrict__ ssort,
                                                   float* __restrict__ out) {
    int wid = (blockIdx.x * blockDim.x + threadIdx.x) >> 6;
    int lane = threadIdx.x & 63;
    int v = wid;
    if (v >= N_NODES) return;
    int q = lane >> 4;
    int eg = lane & 15;
    float dv;
    float4 r = gather_reduce16(y, dinvp, b2, row_start, ssort, v, q, eg, dv);
    int c = lane & 15;
    int row0 = q * 4;
    float partial = 0.f;
    if (c < NCLS) {
        partial = r.x * Wout[(row0 + 0) * NCLS + c]
                + r.y * Wout[(row0 + 1) * NCLS + c]
                + r.z * Wout[(row0 + 2) * NCLS + c]
                + r.w * Wout[(row0 + 3) * NCLS + c];
    }
    partial += __shfl_xor(partial, 16);
    partial += __shfl_xor(partial, 32);
    float lg = (c < NCLS) ? (partial + bout[c]) : -1e30f;
    float mx = lg;
#pragma unroll
    for (int m = 1; m < 16; m <<= 1) mx = fmaxf(mx, __shfl_xor(mx, m));
    float e = (c < NCLS) ? expf(lg - mx) : 0.f;
    float ssum = e;
#pragma unroll
    for (int m = 1; m < 16; m <<= 1) ssum += __shfl_xor(ssum, m);
    if (lane < NCLS) {
        float lse = mx + logf(ssum);
        out[(size_t)v * NCLS + c] = lg - lse;
    }
}

extern "C" void kernel_launch(void* const* d_in, const int* in_sizes, int n_in,
                              void* d_out, int out_size, void* d_ws, size_t ws_size,
                              hipStream_t stream) {
    const float* x    = (const float*)d_in[0];
    const void*  edge = d_in[1];
    const float* W1   = (const float*)d_in[2];
    const float* b1   = (const float*)d_in[3];
    const float* W2   = (const float*)d_in[4];
    const float* b2   = (const float*)d_in[5];
    const float* Wout = (const float*)d_in[6];
    const float* bout = (const float*)d_in[7];
    float* out = (float*)d_out;
    char* ws = (char*)d_ws;

    auto al = [](size_t v) { return (v + 255) & ~(size_t)255; };
    size_t o = 0;
    int*      gcount    = (int*)(ws + o);      o = al(o + (size_t)NBUCK * 4);
    int*      row_start = (int*)(ws + o);      o = al(o + (size_t)(N_NODES + 1) * 4);
    float*    dinv      = (float*)(ws + o);    o = al(o + (size_t)N_NODES * 4);
    frag8*    whibuf    = (frag8*)(ws + o);    o = al(o + (size_t)8 * 64 * 16);
    frag8*    wlobuf    = (frag8*)(ws + o);    o = al(o + (size_t)8 * 64 * 16);
    uint32_t* temp      = (uint32_t*)(ws + o); o = al(o + (size_t)NBUCK * BCAP * 4);
    int*      ssort     = (int*)(ws + o);      o = al(o + (size_t)N_EDGES * 4);
    ushort*   y1buf     = (ushort*)(ws + o);   o = al(o + (size_t)N_NODES * HID * 2);
    ushort*   y2buf     = (ushort*)(ws + o);   o = al(o + (size_t)N_NODES * HID * 2);

    hipMemsetAsync(gcount, 0, (size_t)NBUCK * 4, stream);
    bucket_kernel<<<(N_EDGES + EPB - 1) / EPB, 256, 0, stream>>>(edge, gcount, temp, W1, whibuf, wlobuf);
    build_kernel<<<NBUCK, 256, 0, stream>>>(temp, gcount, row_start, dinv, ssort);
    gemm1_kernel<<<(N_NODES + 127) / 128, 512, 0, stream>>>(x, whibuf, wlobuf, dinv, y1buf);
    aggA_kernel<<<(N_NODES * 64) / 256, 256, 0, stream>>>(y1buf, dinv, b1, W2, row_start, ssort, y2buf);
    aggB_kernel<<<(N_NODES * 64) / 256, 256, 0, stream>>>(y2buf, dinv, b2, Wout, bout, row_start, ssort, out);
}

// Round 10
// 164.079 us; speedup vs baseline: 1.9730x; 1.0507x over previous
//
#include <hip/hip_runtime.h>
#include <hip/hip_bf16.h>
#include <stdint.h>

#define N_NODES 100000
#define N_EDGES 3200000
#define F_IN 256
#define HID 16
#define NCLS 7

#define NBUCK 391        // ceil(100000 / 256) buckets of 256 nodes (dst >> 8)
#define BCAP 9216        // capacity per bucket (avg 8184 -> ample headroom)
#define EPB 4096         // edges per block in bucket path (8 per thread @512)
#define BUCKET_BLOCKS ((N_EDGES + EPB - 1) / EPB)     // 782
#define GEMM_BLOCKS ((N_NODES + 127) / 128)           // 782

using frag8 = __attribute__((ext_vector_type(8))) short;
using f32x4 = __attribute__((ext_vector_type(4))) float;

__device__ inline short f32_to_bf16_rn(float f) {
    uint32_t u = __float_as_uint(f);
    uint32_t r = (u + 0x7FFF + ((u >> 16) & 1)) >> 16;
    return (short)r;
}
__device__ inline float bf16_to_f32(short s) {
    return __uint_as_float(((uint32_t)(uint16_t)s) << 16);
}
__device__ inline short f32_bf16_native(float f) {
    __hip_bfloat16 h = __float2bfloat16(f);
    union { __hip_bfloat16 b; unsigned short u; } cv;
    cv.b = h;
    return (short)cv.u;
}

// ---------------- K1: bucket-binning blocks ∥ GEMM-noscale blocks ----------
// blocks [0, BUCKET_BLOCKS): bin 4096 edges into 391 dst-buckets (LDS regroup,
//   coalesced bucket-contiguous global writes).
// blocks [BUCKET_BLOCKS, +GEMM_BLOCKS): y1f = x @ W1 (f32, unscaled; dinv not
//   yet known — applied in K2). Per-block W1 hi/lo bf16 fragments via LDS.
__global__ __launch_bounds__(512) void k1_kernel(const void* edge_raw,
                                                 int* gcount, uint32_t* temp,
                                                 const float* __restrict__ x,
                                                 const float* __restrict__ W1,
                                                 float* __restrict__ y1f) {
    __shared__ __align__(16) char smem[31328];
    int t = threadIdx.x;
    if (blockIdx.x < BUCKET_BLOCKS) {
        uint32_t* buf2      = (uint32_t*)smem;            // 16384 B
        uint16_t* bucket_of = (uint16_t*)(smem + 16384);  //  8192 B
        int* cnt   = (int*)(smem + 24576);                //  1564 B
        int* lofs  = (int*)(smem + 26140);                //  1568 B
        int* gbase = (int*)(smem + 27708);                //  1564 B
        int* sh    = (int*)(smem + 29272);                //  2048 B
        int* s_is32 = (int*)(smem + 31320);               //     4 B
        if (t == 0) *s_is32 = 0;
        if (t < NBUCK) cnt[t] = 0;
        __syncthreads();
        uint32_t probe = ((const uint32_t*)edge_raw)[2 * t + 1];
        if (probe) atomicOr(s_is32, 1);
        __syncthreads();
        int is64 = (*s_is32 == 0);
        int e0 = blockIdx.x * EPB;
        int total = min(EPB, N_EDGES - e0);
        uint32_t val[8];
        int bk[8], rk[8];
#pragma unroll
        for (int k = 0; k < 8; ++k) {
            int e = e0 + k * 512 + t;
            if (e < N_EDGES) {
                int s, d;
                if (is64) {
                    const long long* p = (const long long*)edge_raw;
                    s = (int)p[e]; d = (int)p[N_EDGES + e];
                } else {
                    const int* p = (const int*)edge_raw;
                    s = p[e]; d = p[N_EDGES + e];
                }
                int b = d >> 8;
                val[k] = ((uint32_t)s << 8) | (uint32_t)(d & 255);
                bk[k] = b;
                rk[k] = atomicAdd(&cnt[b], 1);
            } else {
                bk[k] = -1;
            }
        }
        __syncthreads();
        // inclusive scan over 512 (cnt[t] for t<391 else 0) -> lofs
        int cv = (t < NBUCK) ? cnt[t] : 0;
        sh[t] = cv;
        __syncthreads();
        for (int off = 1; off < 512; off <<= 1) {
            int a = (t >= off) ? sh[t - off] : 0;
            __syncthreads();
            sh[t] += a;
            __syncthreads();
        }
        if (t < NBUCK) lofs[t] = sh[t] - cv;
        __syncthreads();
#pragma unroll
        for (int k = 0; k < 8; ++k) {
            if (bk[k] >= 0) {
                int p = lofs[bk[k]] + rk[k];
                buf2[p] = val[k];
                bucket_of[p] = (uint16_t)bk[k];
            }
        }
        if (t < NBUCK) {
            int c = cnt[t];
            gbase[t] = c ? atomicAdd(&gcount[t], c) : 0;
        }
        __syncthreads();
        for (int i = t; i < total; i += 512) {
            int b = bucket_of[i];
            int pos = gbase[b] + (i - lofs[b]);
            if (pos < BCAP) temp[(size_t)b * BCAP + pos] = buf2[i];
        }
    } else {
        short* whl = (short*)smem;            // 8192 B
        short* wll = (short*)(smem + 8192);   // 8192 B
        // cooperative W1 hi/lo split into LDS (4096 elements, 8 per thread)
#pragma unroll
        for (int j = 0; j < 8; ++j) {
            int wdx = t * 8 + j;
            float wv = W1[wdx];
            short h = f32_to_bf16_rn(wv);
            short lo = f32_to_bf16_rn(wv - bf16_to_f32(h));
            int k = wdx >> 4, col = wdx & 15;
            int s = k >> 5, kg = (k >> 3) & 3, jj = k & 7;
            int idx = ((s << 6) + (kg << 4) + col) * 8 + jj;
            whl[idx] = h; wll[idx] = lo;
        }
        __syncthreads();
        int lane = t & 63;
        int w = t >> 6;        // wave 0..7, 16 rows each
        int col = lane & 15;
        int kg = lane >> 4;
        frag8 whi[8], wlo[8];
#pragma unroll
        for (int s = 0; s < 8; ++s) {
            whi[s] = *(const frag8*)(whl + (s * 64 + lane) * 8);
            wlo[s] = *(const frag8*)(wll + (s * 64 + lane) * 8);
        }
        int gb = blockIdx.x - BUCKET_BLOCKS;
        int v0 = gb * 128 + w * 16;
        int arow = v0 + col;
        int arow_c = min(arow, N_NODES - 1);
        const float* xrow = x + (size_t)arow_c * F_IN + kg * 8;
        f32x4 acc = {0.f, 0.f, 0.f, 0.f};
#pragma unroll
        for (int s = 0; s < 8; ++s) {
            float4 a = *((const float4*)(xrow + s * 32));
            float4 b = *((const float4*)(xrow + s * 32 + 4));
            frag8 ahi;
            ahi[0] = f32_bf16_native(a.x); ahi[1] = f32_bf16_native(a.y);
            ahi[2] = f32_bf16_native(a.z); ahi[3] = f32_bf16_native(a.w);
            ahi[4] = f32_bf16_native(b.x); ahi[5] = f32_bf16_native(b.y);
            ahi[6] = f32_bf16_native(b.z); ahi[7] = f32_bf16_native(b.w);
            acc = __builtin_amdgcn_mfma_f32_16x16x32_bf16(ahi, wlo[s], acc, 0, 0, 0);
            acc = __builtin_amdgcn_mfma_f32_16x16x32_bf16(ahi, whi[s], acc, 0, 0, 0);
        }
#pragma unroll
        for (int r = 0; r < 4; ++r) {
            int gr = v0 + kg * 4 + r;
            if (gr < N_NODES) y1f[(size_t)gr * HID + col] = acc[r];
        }
    }
}

// ---------------- K2: per-bucket CSR build + y1 scale-to-bf16 --------------
__global__ __launch_bounds__(256) void build_kernel(const uint32_t* temp, const int* gcount,
                                                    int* row_start, float* dinv, int* ssort,
                                                    const float* __restrict__ y1f,
                                                    ushort* __restrict__ y1) {
    __shared__ int hist[256];
    __shared__ int sh[256];
    __shared__ int cur[256];
    __shared__ int wsum[4];
    __shared__ float dinvl[256];
    __shared__ int sbuf[BCAP];
    int b = blockIdx.x;
    int t = threadIdx.x;
    int g0 = (t < NBUCK && t < b) ? gcount[t] : 0;
    int g1 = (t + 256 < NBUCK && t + 256 < b) ? gcount[t + 256] : 0;
    int part = g0 + g1;
#pragma unroll
    for (int m = 1; m < 64; m <<= 1) part += __shfl_xor(part, m);
    if ((t & 63) == 0) wsum[t >> 6] = part;
    int cnt = min(gcount[b], BCAP);
    const uint32_t* tp = temp + (size_t)b * BCAP;
    hist[t] = 0;
    __syncthreads();
    int bs = wsum[0] + wsum[1] + wsum[2] + wsum[3];
    for (int i = t; i < cnt; i += 256) atomicAdd(&hist[tp[i] & 255], 1);
    __syncthreads();
    int dg = hist[t];
    sh[t] = dg;
    __syncthreads();
    for (int off = 1; off < 256; off <<= 1) {
        int a = (t >= off) ? sh[t - off] : 0;
        __syncthreads();
        sh[t] += a;
        __syncthreads();
    }
    int ex = sh[t] - dg;
    int node = b * 256 + t;
    cur[t] = ex;
    float dv = rsqrtf((float)(dg + 1));
    dinvl[t] = dv;
    if (node < N_NODES) {
        row_start[node] = bs + ex;
        dinv[node] = dv;
    }
    __syncthreads();
    for (int i = t; i < cnt; i += 256) {
        uint32_t v = tp[i];
        int pos = atomicAdd(&cur[v & 255], 1);
        sbuf[pos] = (int)(v >> 8);
    }
    __syncthreads();
    for (int i = t; i < cnt; i += 256) ssort[bs + i] = sbuf[i];
    // scale this block's 256 nodes of y1f by dinv and store bf16 y1
    int n0 = b * 256;
    int nv = min(256, N_NODES - n0);
    int cnt4 = nv * 4;  // float4s
    const float4* yin = (const float4*)(y1f + (size_t)n0 * HID);
    ushort4* yout = (ushort4*)(y1 + (size_t)n0 * HID);
    for (int i = t; i < cnt4; i += 256) {
        float4 f = yin[i];
        float d = dinvl[i >> 2];
        ushort4 o;
        o.x = (ushort)f32_bf16_native(f.x * d);
        o.y = (ushort)f32_bf16_native(f.y * d);
        o.z = (ushort)f32_bf16_native(f.z * d);
        o.w = (ushort)f32_bf16_native(f.w * d);
        yout[i] = o;
    }
    if (b == 0 && t == 0) row_start[N_NODES] = N_EDGES;
}

// ---- gather+reduce, 2-edge unrolled (32 edges/iter) for MLP ---------------
__device__ inline float4 gather_reduce16(const ushort* __restrict__ y,
                                         const float* __restrict__ dinvp,
                                         const float* __restrict__ bias,
                                         const int* __restrict__ row_start,
                                         const int* __restrict__ ssort,
                                         int v, int q, int eg, float& dv_out) {
    int start = row_start[v];
    int end = row_start[v + 1];
    float4 acc = make_float4(0.f, 0.f, 0.f, 0.f);
    int base = start;
    for (; base + 32 <= end; base += 32) {
        int2 ss = *((const int2*)(ssort + base + 2 * eg));
        ushort4 y0 = *((const ushort4*)(y + (size_t)ss.x * HID + q * 4));
        ushort4 y1 = *((const ushort4*)(y + (size_t)ss.y * HID + q * 4));
        acc.x += bf16_to_f32((short)y0.x) + bf16_to_f32((short)y1.x);
        acc.y += bf16_to_f32((short)y0.y) + bf16_to_f32((short)y1.y);
        acc.z += bf16_to_f32((short)y0.z) + bf16_to_f32((short)y1.z);
        acc.w += bf16_to_f32((short)y0.w) + bf16_to_f32((short)y1.w);
    }
    for (; base < end; base += 16) {
        int e = base + eg;
        if (e < end) {
            int s = ssort[e];
            ushort4 yv = *((const ushort4*)(y + (size_t)s * HID + q * 4));
            acc.x += bf16_to_f32((short)yv.x);
            acc.y += bf16_to_f32((short)yv.y);
            acc.z += bf16_to_f32((short)yv.z);
            acc.w += bf16_to_f32((short)yv.w);
        }
    }
#pragma unroll
    for (int m = 1; m < 16; m <<= 1) {
        acc.x += __shfl_xor(acc.x, m);
        acc.y += __shfl_xor(acc.y, m);
        acc.z += __shfl_xor(acc.z, m);
        acc.w += __shfl_xor(acc.w, m);
    }
    ushort4 sv = *((const ushort4*)(y + (size_t)v * HID + q * 4));
    float dv = dinvp[v];
    float4 bv = *((const float4*)(bias + q * 4));
    float4 r;
    r.x = fmaxf(dv * (acc.x + bf16_to_f32((short)sv.x)) + bv.x, 0.f);
    r.y = fmaxf(dv * (acc.y + bf16_to_f32((short)sv.y)) + bv.y, 0.f);
    r.z = fmaxf(dv * (acc.z + bf16_to_f32((short)sv.z)) + bv.z, 0.f);
    r.w = fmaxf(dv * (acc.w + bf16_to_f32((short)sv.w)) + bv.w, 0.f);
    dv_out = dv;
    return r;
}

// ---------------- agg layer 1 fused with gemm2: y2 = bf16(dinv*(h1@W2)) ----
__global__ __launch_bounds__(256) void aggA_kernel(const ushort* __restrict__ y,
                                                   const float* __restrict__ dinvp,
                                                   const float* __restrict__ b1,
                                                   const float* __restrict__ W2,
                                                   const int* __restrict__ row_start,
                                                   const int* __restrict__ ssort,
                                                   ushort* __restrict__ y2) {
    int wid = (blockIdx.x * blockDim.x + threadIdx.x) >> 6;
    int lane = threadIdx.x & 63;
    int v = wid;
    if (v >= N_NODES) return;
    int q = lane >> 4;
    int eg = lane & 15;
    float dv;
    float4 r = gather_reduce16(y, dinvp, b1, row_start, ssort, v, q, eg, dv);
    int c = lane & 15;
    int row0 = q * 4;
    float partial = r.x * W2[(row0 + 0) * 16 + c]
                  + r.y * W2[(row0 + 1) * 16 + c]
                  + r.z * W2[(row0 + 2) * 16 + c]
                  + r.w * W2[(row0 + 3) * 16 + c];
    partial += __shfl_xor(partial, 16);
    partial += __shfl_xor(partial, 32);
    if (lane < 16) y2[(size_t)v * HID + c] = (ushort)f32_bf16_native(dv * partial);
}

// ---------------- agg layer 2 fused with output + log_softmax --------------
__global__ __launch_bounds__(256) void aggB_kernel(const ushort* __restrict__ y,
                                                   const float* __restrict__ dinvp,
                                                   const float* __restrict__ b2,
                                                   const float* __restrict__ Wout,
                                                   const float* __restrict__ bout,
                                                   const int* __restrict__ row_start,
                                                   const int* __restrict__ ssort,
                                                   float* __restrict__ out) {
    int wid = (blockIdx.x * blockDim.x + threadIdx.x) >> 6;
    int lane = threadIdx.x & 63;
    int v = wid;
    if (v >= N_NODES) return;
    int q = lane >> 4;
    int eg = lane & 15;
    float dv;
    float4 r = gather_reduce16(y, dinvp, b2, row_start, ssort, v, q, eg, dv);
    int c = lane & 15;
    int row0 = q * 4;
    float partial = 0.f;
    if (c < NCLS) {
        partial = r.x * Wout[(row0 + 0) * NCLS + c]
                + r.y * Wout[(row0 + 1) * NCLS + c]
                + r.z * Wout[(row0 + 2) * NCLS + c]
                + r.w * Wout[(row0 + 3) * NCLS + c];
    }
    partial += __shfl_xor(partial, 16);
    partial += __shfl_xor(partial, 32);
    float lg = (c < NCLS) ? (partial + bout[c]) : -1e30f;
    float mx = lg;
#pragma unroll
    for (int m = 1; m < 16; m <<= 1) mx = fmaxf(mx, __shfl_xor(mx, m));
    float e = (c < NCLS) ? expf(lg - mx) : 0.f;
    float ssum = e;
#pragma unroll
    for (int m = 1; m < 16; m <<= 1) ssum += __shfl_xor(ssum, m);
    if (lane < NCLS) {
        float lse = mx + logf(ssum);
        out[(size_t)v * NCLS + c] = lg - lse;
    }
}

extern "C" void kernel_launch(void* const* d_in, const int* in_sizes, int n_in,
                              void* d_out, int out_size, void* d_ws, size_t ws_size,
                              hipStream_t stream) {
    const float* x    = (const float*)d_in[0];
    const void*  edge = d_in[1];
    const float* W1   = (const float*)d_in[2];
    const float* b1   = (const float*)d_in[3];
    const float* W2   = (const float*)d_in[4];
    const float* b2   = (const float*)d_in[5];
    const float* Wout = (const float*)d_in[6];
    const float* bout = (const float*)d_in[7];
    float* out = (float*)d_out;
    char* ws = (char*)d_ws;

    auto al = [](size_t v) { return (v + 255) & ~(size_t)255; };
    size_t o = 0;
    int*      gcount    = (int*)(ws + o);      o = al(o + (size_t)NBUCK * 4);
    int*      row_start = (int*)(ws + o);      o = al(o + (size_t)(N_NODES + 1) * 4);
    float*    dinv      = (float*)(ws + o);    o = al(o + (size_t)N_NODES * 4);
    uint32_t* temp      = (uint32_t*)(ws + o); o = al(o + (size_t)NBUCK * BCAP * 4);
    int*      ssort     = (int*)(ws + o);      o = al(o + (size_t)N_EDGES * 4);
    float*    y1fbuf    = (float*)(ws + o);    o = al(o + (size_t)N_NODES * HID * 4);
    ushort*   y1buf     = (ushort*)(ws + o);   o = al(o + (size_t)N_NODES * HID * 2);
    ushort*   y2buf     = (ushort*)(ws + o);   o = al(o + (size_t)N_NODES * HID * 2);

    hipMemsetAsync(gcount, 0, (size_t)NBUCK * 4, stream);
    k1_kernel<<<BUCKET_BLOCKS + GEMM_BLOCKS, 512, 0, stream>>>(edge, gcount, temp, x, W1, y1fbuf);
    build_kernel<<<NBUCK, 256, 0, stream>>>(temp, gcount, row_start, dinv, ssort, y1fbuf, y1buf);
    aggA_kernel<<<(N_NODES * 64) / 256, 256, 0, stream>>>(y1buf, dinv, b1, W2, row_start, ssort, y2buf);
    aggB_kernel<<<(N_NODES * 64) / 256, 256, 0, stream>>>(y2buf, dinv, b2, Wout, bout, row_start, ssort, out);
}